// Round 4
// baseline (929.355 us; speedup 1.0000x reference)
//
#include <hip/hip_runtime.h>
#include <math.h>

#define HW 36864
#define CD 192
#define NH 6
#define HDIM 32
#define HIDD 768

typedef unsigned short u16;
typedef __attribute__((ext_vector_type(8))) short bf16x8;
typedef __attribute__((ext_vector_type(4))) float f32x4;
typedef __attribute__((ext_vector_type(8))) _Float16 f16x8;
typedef __attribute__((ext_vector_type(2))) __fp16 fp16x2;

__device__ __forceinline__ float gelu_f(float x) {
  return 0.5f * x * (1.0f + erff(x * 0.70710678118654752f));
}
__device__ __forceinline__ u16 f2b(float f) {
  union { float f; unsigned u; } v; v.f = f;
  unsigned r = v.u + 0x7fff + ((v.u >> 16) & 1);   // RNE
  return (u16)(r >> 16);
}
__device__ __forceinline__ float b2f(u16 b) {
  union { unsigned u; float f; } v; v.u = ((unsigned)b) << 16;
  return v.f;
}
// packed f32->f16 (RTZ), result as the raw 32-bit word
__device__ __forceinline__ unsigned pkrtz_u(float a, float b) {
  union { fp16x2 h; unsigned u; } cv;
  cv.h = __builtin_amdgcn_cvt_pkrtz(a, b);
  return cv.u;
}

// ---------- fused LayerNorm + transpose: fp32 CM in -> bf16 TM out ----------
__global__ __launch_bounds__(256)
void lnt_kernel(const float* __restrict__ in, const float* __restrict__ g,
                const float* __restrict__ b, u16* __restrict__ outTM)
{
  __shared__ float tile[64][193];
  __shared__ float red[64][8];
  __shared__ float2 stat2[64];
  __shared__ float gb[384];
  const int tid = threadIdx.x;
  const int part = tid >> 6, tk = tid & 63;
  const int tok = blockIdx.x * 64 + tk;
  if (tid < 192) { gb[tid] = g[tid]; gb[192 + tid] = b[tid]; }
  float s = 0.f, sq = 0.f;
  for (int c = part * 48; c < part * 48 + 48; ++c) {
    float v = in[(size_t)c * HW + tok];
    tile[tk][c] = v; s += v; sq += v * v;
  }
  red[tk][part] = s; red[tk][4 + part] = sq;
  __syncthreads();
  if (tid < 64) {
    float ss = red[tid][0] + red[tid][1] + red[tid][2] + red[tid][3];
    float qq = red[tid][4] + red[tid][5] + red[tid][6] + red[tid][7];
    float m = ss * (1.0f / CD);
    float var = fmaxf(qq * (1.0f / CD) - m * m, 0.f);
    stat2[tid] = make_float2(m, rsqrtf(var + 1e-5f));
  }
  __syncthreads();
  unsigned* op = (unsigned*)outTM + (size_t)blockIdx.x * 6144;
  #pragma unroll
  for (int r = 0; r < 24; ++r) {
    int idx = tid + r * 256;
    int tok2 = idx / 96, dc = idx - tok2 * 96;
    float2 st = stat2[tok2];
    int c = dc * 2;
    float v0 = (tile[tok2][c] - st.x) * st.y * gb[c] + gb[192 + c];
    float v1 = (tile[tok2][c + 1] - st.x) * st.y * gb[c + 1] + gb[192 + c + 1];
    op[idx] = (unsigned)f2b(v0) | ((unsigned)f2b(v1) << 16);
  }
}

// ---------- bf16 CM [C][HW] -> bf16 TM [HW][C] transpose (for y2, C=768) ----------
__global__ __launch_bounds__(256)
void trans_kernel(const u16* __restrict__ in, u16* __restrict__ out, int C)
{
  __shared__ u16 ls[64][34];
  const int m0 = blockIdx.x * 64, c0 = blockIdx.y * 32;
  const int t = threadIdx.x;
  #pragma unroll
  for (int r = 0; r < 4; ++r) {
    int idx = t + r * 256;
    int c = idx >> 5, dm = idx & 31;
    unsigned d = *(const unsigned*)(in + (size_t)(c0 + c) * HW + m0 + dm * 2);
    ls[dm * 2][c] = (u16)d;
    ls[dm * 2 + 1][c] = (u16)(d >> 16);
  }
  __syncthreads();
  #pragma unroll
  for (int r = 0; r < 4; ++r) {
    int idx = t + r * 256;
    int m = idx >> 4, dc = idx & 15;
    unsigned d = (unsigned)ls[m][dc * 2] | ((unsigned)ls[m][dc * 2 + 1] << 16);
    *(unsigned*)(out + (size_t)(m0 + m) * C + c0 + dc * 2) = d;
  }
}

// ---------- weight prep: fp32 [K][N] -> bf16 [N][K] ----------
__global__ __launch_bounds__(256)
void wtrans_kernel(const float* __restrict__ in, u16* __restrict__ out, int K, int N)
{
  __shared__ float ls[32][33];
  const int k0 = blockIdx.x * 32, n0 = blockIdx.y * 32;
  const int t = threadIdx.x;
  #pragma unroll
  for (int r = 0; r < 4; ++r) {
    int idx = t + r * 256;
    int k = idx >> 5, n = idx & 31;
    ls[k][n] = in[(size_t)(k0 + k) * N + n0 + n];
  }
  __syncthreads();
  #pragma unroll
  for (int r = 0; r < 4; ++r) {
    int idx = t + r * 256;
    int n = idx >> 5, k = idx & 31;
    out[(size_t)(n0 + n) * K + k0 + k] = f2b(ls[k][n]);
  }
}

// 4 square 192x192 weights in one launch
__global__ __launch_bounds__(256)
void wtrans4_kernel(const float* __restrict__ w0, const float* __restrict__ w1,
                    const float* __restrict__ w2, const float* __restrict__ w3,
                    u16* __restrict__ out)
{
  __shared__ float ls[32][33];
  const int z = blockIdx.z;
  const float* in = (z == 0) ? w0 : (z == 1 ? w1 : (z == 2 ? w2 : w3));
  u16* op = out + (size_t)z * CD * CD;
  const int k0 = blockIdx.x * 32, n0 = blockIdx.y * 32;
  const int t = threadIdx.x;
  #pragma unroll
  for (int r = 0; r < 4; ++r) {
    int idx = t + r * 256;
    int k = idx >> 5, n = idx & 31;
    ls[k][n] = in[(size_t)(k0 + k) * CD + n0 + n];
  }
  __syncthreads();
  #pragma unroll
  for (int r = 0; r < 4; ++r) {
    int idx = t + r * 256;
    int n = idx >> 5, k = idx & 31;
    op[(size_t)(n0 + n) * CD + k0 + k] = f2b(ls[k][n]);
  }
}

// ---------- bf16 MFMA GEMM: D[m][n] = A[m][:].Wt[n][:] + epilogue ----------
// MODE 0: QKV  -> bf16 CM out, +bias, q-segment scaled
// MODE 1: PROJ -> fp32 CM out, +bias +aux (fp32 CM)
// MODE 2: FC1  -> bf16 CM out, +bias, GELU
// MODE 3: FC2  -> fp32 TM out, +bias +aux (fp32 CM)
template<int MODE>
__global__ __launch_bounds__(256, 4)
void mgemm_kernel(const u16* __restrict__ A,
                  const u16* __restrict__ W0, const u16* __restrict__ W1, const u16* __restrict__ W2,
                  const float* __restrict__ b0, const float* __restrict__ b1, const float* __restrict__ b2,
                  const float* __restrict__ aux, void* __restrict__ outv,
                  int K, int segN)
{
  const int n0 = blockIdx.x * 64;
  const int m0 = blockIdx.y * 128;
  const int seg = n0 / segN;
  const u16* Wp = (seg == 0) ? W0 : (seg == 1 ? W1 : W2);
  const float* biasp = (seg == 0) ? b0 : (seg == 1 ? b1 : b2);
  const int nl0 = n0 - seg * segN;

  __shared__ u16 As[128 * 32];
  __shared__ u16 Bs[64 * 32];

  const int tid = threadIdx.x;
  const int lane = tid & 63, wave = tid >> 6;
  const int wm = (wave >> 1) * 64, wn = (wave & 1) * 32;
  const int fm = lane & 15, fq = lane >> 4;
  const int ar = tid >> 2, akq = tid & 3;

  f32x4 acc[4][2];
  #pragma unroll
  for (int i = 0; i < 4; ++i) { acc[i][0] = (f32x4)(0.f); acc[i][1] = (f32x4)(0.f); }

  uint4 rA0, rA1, rB, nA0, nA1, nB;
  rA0 = *(const uint4*)(A + (size_t)(m0 + ar) * K + akq * 8);
  rA1 = *(const uint4*)(A + (size_t)(m0 + ar + 64) * K + akq * 8);
  rB  = *(const uint4*)(Wp + (size_t)(nl0 + ar) * K + akq * 8);

  for (int k0 = 0; k0 < K; k0 += 32) {
    *(uint4*)(&As[ar * 32 + akq * 8]) = rA0;
    *(uint4*)(&As[(ar + 64) * 32 + akq * 8]) = rA1;
    *(uint4*)(&Bs[ar * 32 + akq * 8]) = rB;
    __syncthreads();
    const int kn = (k0 + 32 < K) ? k0 + 32 : k0;
    nA0 = *(const uint4*)(A + (size_t)(m0 + ar) * K + kn + akq * 8);
    nA1 = *(const uint4*)(A + (size_t)(m0 + ar + 64) * K + kn + akq * 8);
    nB  = *(const uint4*)(Wp + (size_t)(nl0 + ar) * K + kn + akq * 8);
    bf16x8 af[4], bf[2];
    #pragma unroll
    for (int mt = 0; mt < 4; ++mt)
      af[mt] = *(const bf16x8*)(&As[(wm + mt * 16 + fm) * 32 + fq * 8]);
    #pragma unroll
    for (int nt = 0; nt < 2; ++nt)
      bf[nt] = *(const bf16x8*)(&Bs[(wn + nt * 16 + fm) * 32 + fq * 8]);
    #pragma unroll
    for (int mt = 0; mt < 4; ++mt)
      #pragma unroll
      for (int nt = 0; nt < 2; ++nt)
        acc[mt][nt] = __builtin_amdgcn_mfma_f32_16x16x32_bf16(af[mt], bf[nt], acc[mt][nt], 0, 0, 0);
    __syncthreads();
    rA0 = nA0; rA1 = nA1; rB = nB;
  }

  #pragma unroll
  for (int nt = 0; nt < 2; ++nt) {
    const int n = n0 + wn + nt * 16 + fm;
    const float bia = biasp[nl0 + wn + nt * 16 + fm];
    #pragma unroll
    for (int mt = 0; mt < 4; ++mt) {
      const int mb = m0 + wm + mt * 16 + fq * 4;
      float o[4];
      #pragma unroll
      for (int r = 0; r < 4; ++r) o[r] = acc[mt][nt][r] + bia;
      if (MODE == 0) {
        const float sc = (seg == 0) ? 0.17677669529663689f : 1.0f;  // q pre-scaled by hd^-0.5
        u16 h0 = f2b(o[0] * sc), h1 = f2b(o[1] * sc), h2 = f2b(o[2] * sc), h3 = f2b(o[3] * sc);
        uint2 pk = make_uint2((unsigned)h0 | ((unsigned)h1 << 16), (unsigned)h2 | ((unsigned)h3 << 16));
        *(uint2*)((u16*)outv + (size_t)n * HW + mb) = pk;
      } else if (MODE == 1) {
        const float4 ax = *(const float4*)(aux + (size_t)n * HW + mb);
        *(float4*)((float*)outv + (size_t)n * HW + mb) =
            make_float4(o[0] + ax.x, o[1] + ax.y, o[2] + ax.z, o[3] + ax.w);
      } else if (MODE == 2) {
        u16 h0 = f2b(gelu_f(o[0])), h1 = f2b(gelu_f(o[1]));
        u16 h2 = f2b(gelu_f(o[2])), h3 = f2b(gelu_f(o[3]));
        uint2 pk = make_uint2((unsigned)h0 | ((unsigned)h1 << 16), (unsigned)h2 | ((unsigned)h3 << 16));
        *(uint2*)((u16*)outv + (size_t)n * HW + mb) = pk;
      } else {
        const float4 ax = *(const float4*)(aux + (size_t)n * HW + mb);
        float* op = (float*)outv;
        op[(size_t)(mb + 0) * CD + n] = o[0] + ax.x;
        op[(size_t)(mb + 1) * CD + n] = o[1] + ax.y;
        op[(size_t)(mb + 2) * CD + n] = o[2] + ax.z;
        op[(size_t)(mb + 3) * CD + n] = o[3] + ax.w;
      }
    }
  }
}

// ---------- depthwise 5x5 conv + bias + exact GELU (+optional residual) ----------
template<bool ADD>
__global__ __launch_bounds__(256)
void dwconv_kernel(const u16* __restrict__ in, const float* __restrict__ w,
                   const float* __restrict__ bias, u16* __restrict__ out)
{
  const int plane = blockIdx.z;
  const int bx = blockIdx.x * 64, by = blockIdx.y * 4;
  __shared__ float tile[8][68];
  __shared__ float ws[26];
  const int tid = threadIdx.x;
  if (tid < 26) ws[tid] = (tid < 25) ? w[plane * 25 + tid] : bias[plane];
  const u16* ip = in + (size_t)plane * HW;
  for (int e = tid; e < 544; e += 256) {
    int r = e / 68, cc = e - r * 68;
    int gy = by + r - 2, gx = bx + cc - 2;
    tile[r][cc] = (gy >= 0 && gy < 192 && gx >= 0 && gx < 192) ? b2f(ip[gy * 192 + gx]) : 0.f;
  }
  __syncthreads();
  const int tx = tid & 63, ty = tid >> 6;
  float acc = 0.f;
  #pragma unroll
  for (int dy = 0; dy < 5; ++dy)
    #pragma unroll
    for (int dx = 0; dx < 5; ++dx)
      acc = fmaf(tile[ty + dy][tx + dx], ws[dy * 5 + dx], acc);
  float v = gelu_f(acc + ws[25]);
  if (ADD) v += tile[ty + 2][tx + 2];
  out[(size_t)plane * HW + (by + ty) * 192 + bx + tx] = f2b(v);
}

// ---------- fused window attention v6 ----------
// v5b + full-pass prefetch windows: pfa issued at pass TOP (window = whole
// pass), Q double-buffered one pass ahead, rpi gather above the top barrier,
// no pass-7 wrap waste.
__global__ __launch_bounds__(512, 6)
void attn_kernel(const u16* __restrict__ qg, const u16* __restrict__ kg,
                 const u16* __restrict__ vg, const u16* __restrict__ vlg,
                 const float* __restrict__ pfa_v, const int* __restrict__ pfa_i,
                 const int* __restrict__ rpi, const float* __restrict__ rpb_t,
                 u16* __restrict__ attn_out)
{
  const int h = blockIdx.x;
  const int win = blockIdx.y;
  const int wy = (win / 12) * 16;
  const int wx = (win - (win / 12) * 12) * 16;
  const size_t hb = (size_t)h * HDIM * HW;

  __shared__ float Sb[32][262];   // scores / P rows, stride 1048B   33536 B (aliased as K staging [256][40] u16)
  __shared__ u16 vT[32][264];     // V^T [d][j] f16 bits             16896 B
  __shared__ u16 rpb_h[962];      // rpb bf16                         1924 B
                                  // total 52356 -> 52736 rounded -> 3 blk/CU

  const int tid = threadIdx.x;
  const int lane = tid & 63, wave = tid >> 6;
  const int fm = lane & 15, fq = lane >> 4;

  for (int r = tid; r < 961; r += 512) rpb_h[r] = f2b(rpb_t[r * 6 + h]);

  // stage K [256][40] u16 into Sb bytes, V^T (f16 bits) into vT
  u16* kst = (u16*)&Sb[0][0];
  #pragma unroll
  for (int r = 0; r < 8; ++r) {
    int idx = tid + r * 512;
    int d = idx >> 7, jp = idx & 127, j = jp * 2;
    int pg = (wy + (j >> 4)) * 192 + (wx + (j & 15));
    ushort2 kv = *(const ushort2*)(kg + hb + (size_t)d * HW + pg);
    kst[j * 40 + d] = kv.x; kst[(j + 1) * 40 + d] = kv.y;
    ushort2 vv = *(const ushort2*)(vg + hb + (size_t)d * HW + pg);
    *(unsigned*)&vT[d][j] = pkrtz_u(b2f(vv.x), b2f(vv.y));
  }
  __syncthreads();

  // hoist K fragments (pass-invariant) into 16 VGPRs
  bf16x8 kf[4];
  #pragma unroll
  for (int t = 0; t < 4; ++t) {
    const int j0 = ((wave >> 1) * 4 + t) * 16;
    kf[t] = *(const bf16x8*)&kst[(j0 + fm) * 40 + fq * 8];
  }
  // (pass-0 top barrier orders these reads before Sb score writes)

  const size_t wb = ((size_t)win * NH + h) * 256;
  const unsigned long long lmlt = (1ull << lane) - 1ull;
  const unsigned KMASK = 0xFFFFF800u;   // 21-bit selection key (bits 31..11)

  // preload pass-0 pfa
  int pj1[4], pj2[4]; float pv1[4], pv2[4];
  #pragma unroll
  for (int u = 0; u < 4; ++u) {
    const size_t base = (wb + (size_t)(u * 8 + wave)) * 128;
    pj1[u] = pfa_i[base + lane];  pj2[u] = pfa_i[base + 64 + lane];
    pv1[u] = pfa_v[base + lane];  pv2[u] = pfa_v[base + 64 + lane];
  }
  // preload pass-0 Q fragment (q already scaled by hd^-0.5)
  union quni { bf16x8 v; u16 hh[8]; };
  quni qcur, qnxt;
  {
    const int pgq = (wy + (wave & 1)) * 192 + wx + fm;
    #pragma unroll
    for (int e = 0; e < 8; ++e)
      qcur.hh[e] = qg[hb + (size_t)(fq * 8 + e) * HW + pgq];
  }

  for (int pass = 0; pass < 8; ++pass) {
    // A: issue next-pass Q (consumed next B; window = full pass)
    if (pass < 7) {
      const int pgq = (wy + (pass + 1) * 2 + (wave & 1)) * 192 + wx + fm;
      #pragma unroll
      for (int e = 0; e < 8; ++e)
        qnxt.hh[e] = qg[hb + (size_t)(fq * 8 + e) * HW + pgq];
    }
    // A: issue next-pass pfa (consumed next C; window = full pass)
    int npj1[4], npj2[4]; float npv1[4], npv2[4];
    if (pass < 7) {
      #pragma unroll
      for (int u = 0; u < 4; ++u) {
        const size_t base = (wb + (size_t)((pass + 1) * 32 + u * 8 + wave)) * 128;
        npj1[u] = pfa_i[base + lane];  npj2[u] = pfa_i[base + 64 + lane];
        npv1[u] = pfa_v[base + lane];  npv2[u] = pfa_v[base + 64 + lane];
      }
    }
    // vl prefetch for this pass's D epilogue (wave<4 only)
    float vlv[4];
    if (wave < 4) {
      const int mt = wave & 1, nt = wave >> 1;
      const int pgo = (wy + pass * 2 + nt) * 192 + wx + fm;
      const int d0 = mt * 16 + fq * 4;
      #pragma unroll
      for (int e = 0; e < 4; ++e)
        vlv[e] = b2f(vlg[hb + (size_t)(d0 + e) * HW + pgo]);
    }
    // rpi gather for this pass (pj resident since prev pass; covered by barrier+B)
    int rbi1[4], rbi2[4];
    #pragma unroll
    for (int u = 0; u < 4; ++u) {
      const int i = pass * 32 + u * 8 + wave;
      rbi1[u] = rpi[i * 256 + pj1[u]];
      rbi2[u] = rpi[i * 256 + pj2[u]];
    }
    __syncthreads();   // prev-pass D reads of Sb done (and pass-0 kf reads)

    // B: scores via MFMA -> Sb
    #pragma unroll
    for (int t = 0; t < 4; ++t) {
      f32x4 c = __builtin_amdgcn_mfma_f32_16x16x32_bf16(qcur.v, kf[t], (f32x4)(0.f), 0, 0, 0);
      const int col = ((wave >> 1) * 4 + t) * 16 + fm;
      const int rowb = (wave & 1) * 16 + fq * 4;
      Sb[rowb + 0][col] = c[0]; Sb[rowb + 1][col] = c[1];
      Sb[rowb + 2][col] = c[2]; Sb[rowb + 3][col] = c[3];
    }
    __syncthreads();

    // C: batched 4-query phases (each wave owns rows u*8+wave)
    float s1[4], s2[4];
    #pragma unroll
    for (int u = 0; u < 4; ++u) {
      const int iq = u * 8 + wave;
      s1[u] = Sb[iq][pj1[u]] + b2f(rpb_h[rbi1[u]]);
      s2[u] = Sb[iq][pj2[u]] + b2f(rpb_h[rbi2[u]]);
    }
    // zero own rows (scores consumed); becomes the P scatter target
    {
      const float2 z2 = make_float2(0.f, 0.f);
      #pragma unroll
      for (int u = 0; u < 4; ++u) {
        const int iq = u * 8 + wave;
        *(float2*)&Sb[iq][lane * 4]     = z2;
        *(float2*)&Sb[iq][lane * 4 + 2] = z2;
      }
    }
    float mx[4];
    #pragma unroll
    for (int u = 0; u < 4; ++u) mx[u] = fmaxf(s1[u], s2[u]);
    #pragma unroll
    for (int o = 32; o > 0; o >>= 1)
      #pragma unroll
      for (int u = 0; u < 4; ++u) mx[u] = fmaxf(mx[u], __shfl_xor(mx[u], o));
    float e1[4], e2[4], sA[4], sB[4];
    #pragma unroll
    for (int u = 0; u < 4; ++u) {
      e1[u] = expf(s1[u] - mx[u]); e2[u] = expf(s2[u] - mx[u]);
      sA[u] = e1[u] + e2[u];
      sB[u] = e1[u] * pv1[u] + e2[u] * pv2[u];
    }
    #pragma unroll
    for (int o = 32; o > 0; o >>= 1)
      #pragma unroll
      for (int u = 0; u < 4; ++u) { sA[u] += __shfl_xor(sA[u], o); sB[u] += __shfl_xor(sB[u], o); }
    unsigned ub1[4], ub2[4]; float a1[4], a2[4];
    #pragma unroll
    for (int u = 0; u < 4; ++u) {
      const float rs = 1.0f / sA[u];
      const float rden = 1.0f / (sB[u] * rs + 1e-10f);
      a1[u] = (e1[u] * rs * pv1[u] + 1e-10f) * rden;
      a2[u] = (e2[u] * rs * pv2[u] + 1e-10f) * rden;
      ub1[u] = __float_as_uint(a1[u]); ub2[u] = __float_as_uint(a2[u]);
    }
    // branchless batched radix select on 19-bit key (a < 2 => bit30 == 0)
    unsigned thr[4] = {0u, 0u, 0u, 0u};
    #pragma unroll 1
    for (int bit = 29; bit >= 11; --bit) {
      #pragma unroll
      for (int u = 0; u < 4; ++u) {
        const unsigned cand = thr[u] | (1u << bit);
        const int cnt = (int)__popcll(__ballot(ub1[u] >= cand)) +
                        (int)__popcll(__ballot(ub2[u] >= cand));
        thr[u] = (cnt >= 64) ? cand : thr[u];
      }
    }
    // tie-break on masked key (position order, matches jax top_k) and scatter-sum
    #pragma unroll
    for (int u = 0; u < 4; ++u) {
      const int iq = u * 8 + wave;
      const unsigned kb1 = ub1[u] & KMASK, kb2 = ub2[u] & KMASK;
      const bool gt1 = kb1 > thr[u], gt2 = kb2 > thr[u];
      const bool eq1 = kb1 == thr[u], eq2 = kb2 == thr[u];
      const unsigned long long meq1 = __ballot(eq1), meq2 = __ballot(eq2);
      const int need = 64 - (int)__popcll(__ballot(gt1)) - (int)__popcll(__ballot(gt2));
      const bool sel1 = gt1 || (eq1 && (int)__popcll(meq1 & lmlt) < need);
      const bool sel2 = gt2 || (eq2 && ((int)__popcll(meq1) + (int)__popcll(meq2 & lmlt)) < need);
      if (sel1) atomicAdd(&Sb[iq][pj1[u]], a1[u]);
      if (sel2) atomicAdd(&Sb[iq][pj2[u]], a2[u]);
    }
    __syncthreads();

    // D: O = V^T (32d x 256j) . P^T (256j x 32i), single f16 MFMA per k0
    if (wave < 4) {
      const int mt = wave & 1, nt = wave >> 1;
      f32x4 acc = (f32x4)(0.f);
      #pragma unroll
      for (int k0 = 0; k0 < 8; ++k0) {
        const f16x8 av = *(const f16x8*)&vT[mt * 16 + fm][k0 * 32 + fq * 8];
        const float* pr = &Sb[nt * 16 + fm][k0 * 32 + fq * 8];
        const float2 p01 = *(const float2*)(pr + 0);
        const float2 p23 = *(const float2*)(pr + 2);
        const float2 p45 = *(const float2*)(pr + 4);
        const float2 p67 = *(const float2*)(pr + 6);
        union { f16x8 v; unsigned q[4]; } bp;
        bp.q[0] = pkrtz_u(p01.x, p01.y);
        bp.q[1] = pkrtz_u(p23.x, p23.y);
        bp.q[2] = pkrtz_u(p45.x, p45.y);
        bp.q[3] = pkrtz_u(p67.x, p67.y);
        acc = __builtin_amdgcn_mfma_f32_16x16x32_f16(av, bp.v, acc, 0, 0, 0);
      }
      // epilogue: D row = d-within-tile, col = i-within-tile
      const int pgo = (wy + pass * 2 + nt) * 192 + wx + fm;
      const int d0 = mt * 16 + fq * 4;
      const float r0 = acc[0] + vlv[0];
      const float r1 = acc[1] + vlv[1];
      const float r2 = acc[2] + vlv[2];
      const float r3 = acc[3] + vlv[3];
      const unsigned o01 = (unsigned)f2b(r0) | ((unsigned)f2b(r1) << 16);
      const unsigned o23 = (unsigned)f2b(r2) | ((unsigned)f2b(r3) << 16);
      *(uint2*)(attn_out + (size_t)pgo * CD + h * HDIM + d0) = make_uint2(o01, o23);
    }
    // rotate pipelines (waves 4-7 reach here during waves 0-3's D)
    if (pass < 7) {
      qcur = qnxt;
      #pragma unroll
      for (int u = 0; u < 4; ++u) {
        pj1[u] = npj1[u]; pj2[u] = npj2[u];
        pv1[u] = npv1[u]; pv2[u] = npv2[u];
      }
    }
  }
}

// ---------- launch ----------
extern "C" void kernel_launch(void* const* d_in, const int* in_sizes, int n_in,
                              void* d_out, int out_size, void* d_ws, size_t ws_size,
                              hipStream_t stream)
{
  (void)in_sizes; (void)n_in; (void)out_size; (void)ws_size;
  const float* features = (const float*)d_in[0];
  const float* pfa_v    = (const float*)d_in[1];
  const int*   pfa_i    = (const int*)d_in[2];
  const int*   rpi      = (const int*)d_in[3];
  const float* ln1_g    = (const float*)d_in[4];
  const float* ln1_b    = (const float*)d_in[5];
  const float* Wq_w     = (const float*)d_in[6];
  const float* Wq_b     = (const float*)d_in[7];
  const float* Wk_w     = (const float*)d_in[8];
  const float* Wk_b     = (const float*)d_in[9];
  const float* Wv_w     = (const float*)d_in[10];
  const float* Wv_b     = (const float*)d_in[11];
  const float* lepe_w   = (const float*)d_in[12];
  const float* lepe_b   = (const float*)d_in[13];
  const float* rpb_t    = (const float*)d_in[14];
  const float* proj_w   = (const float*)d_in[15];
  const float* proj_b   = (const float*)d_in[16];
  const float* ln2_g    = (const float*)d_in[17];
  const float* ln2_b    = (const float*)d_in[18];
  const float* fc1_w    = (const float*)d_in[19];
  const float* fc1_b    = (const float*)d_in[20];
  const float* dw_w     = (const float*)d_in[21];
  const float* dw_b     = (const float*)d_in[22];
  const float* fc2_w    = (const float*)d_in[23];
  const float* fc2_b    = (const float*)d_in[24];

  char* ws = (char*)d_ws;
  const size_t S  = (size_t)HW * CD;
  const size_t SB = S * 4;
  u16*   xnt    = (u16*)(ws);                         // [0, 0.5SB) bf16 TM
  u16*   qkvb   = (u16*)(ws + SB / 2);                // [0.5SB, 2SB) bf16 CM (q scaled, k, v)
  u16*   q_ = qkvb; u16* k_ = qkvb + S; u16* v_ = qkvb + 2 * S;
  u16*   vl     = (u16*)(ws + 2 * SB);                // [2SB, 2.5SB)
  u16*   attn_o = (u16*)(ws + 2 * SB + SB / 2);       // [2.5SB, 3SB) bf16 TM
  float* x2     = (float*)(ws + 3 * SB);              // [3SB, 4SB) fp32 CM, live to end
  u16*   xn2t   = (u16*)(ws + 4 * SB);                // [4SB, 4.5SB)
  u16*   y_     = (u16*)(ws + 4 * SB + SB / 2);       // [4.5SB, 6.5SB) bf16 CM 768xHW
  u16*   y2_    = (u16*)(ws + 6 * SB + SB / 2);       // [6.5SB, 8.5SB)
  u16*   y2t    = (u16*)(ws);                         // [0, 2SB) reuse (xnt/qkvb dead)
  u16*   wqt  = (u16*)(ws + 8 * SB + SB / 2);
  u16*   wkt  = wqt + 36864;
  u16*   wvt  = wkt + 36864;
  u16*   wpt  = wvt + 36864;
  u16*   wf1t = wpt + 36864;      // [768][192]
  u16*   wf2t = wf1t + 147456;    // [192][768]
  float* out = (float*)d_out;

  // 0) weight prep
  wtrans4_kernel<<<dim3(6, 6, 4), 256, 0, stream>>>(Wq_w, Wk_w, Wv_w, proj_w, wqt);
  wtrans_kernel<<<dim3(6, 24), 256, 0, stream>>>(fc1_w, wf1t, 192, 768);
  wtrans_kernel<<<dim3(24, 6), 256, 0, stream>>>(fc2_w, wf2t, 768, 192);
  // 1) LN1 fused transpose -> bf16 TM
  lnt_kernel<<<dim3(HW / 64), 256, 0, stream>>>(features, ln1_g, ln1_b, xnt);
  // 2) QKV MFMA -> bf16 CM (q scaled)
  mgemm_kernel<0><<<dim3(9, HW / 128), 256, 0, stream>>>(xnt, wqt, wkt, wvt, Wq_b, Wk_b, Wv_b,
                                                         nullptr, qkvb, 192, 192);
  // 3) LePE dwconv on v (bf16)
  dwconv_kernel<false><<<dim3(3, 48, 192), 256, 0, stream>>>(v_, lepe_w, lepe_b, vl);
  // 4) window attention -> bf16 TM
  attn_kernel<<<dim3(6, 144), 512, 0, stream>>>(q_, k_, v_, vl, pfa_v, pfa_i, rpi, rpb_t, attn_o);
  // 5) proj + shortcut -> fp32 CM x2
  mgemm_kernel<1><<<dim3(3, HW / 128), 256, 0, stream>>>(attn_o, wpt, wpt, wpt, proj_b, proj_b, proj_b,
                                                         features, x2, 192, 1 << 30);
  // 6) LN2 fused transpose -> bf16 TM
  lnt_kernel<<<dim3(HW / 64), 256, 0, stream>>>(x2, ln2_g, ln2_b, xn2t);
  // 7) fc1 + GELU -> bf16 CM y
  mgemm_kernel<2><<<dim3(12, HW / 128), 256, 0, stream>>>(xn2t, wf1t, wf1t, wf1t, fc1_b, fc1_b, fc1_b,
                                                          nullptr, y_, 192, 1 << 30);
  // 8) y2 = y + gelu(dwconv(y)+b) -> bf16 CM
  dwconv_kernel<true><<<dim3(3, 48, 768), 256, 0, stream>>>(y_, dw_w, dw_b, y2_);
  // 9) transpose y2 -> bf16 TM
  trans_kernel<<<dim3(HW / 64, 24), 256, 0, stream>>>(y2_, y2t, HIDD);
  // 10) fc2 + x2 residual -> fp32 TM final output
  mgemm_kernel<3><<<dim3(3, HW / 128), 256, 0, stream>>>(y2t, wf2t, wf2t, wf2t, fc2_b, fc2_b, fc2_b,
                                                         x2, out, 768, 1 << 30);
}

// Round 6
// 777.915 us; speedup vs baseline: 1.1947x; 1.1947x over previous
//
#include <hip/hip_runtime.h>
#include <math.h>

#define HW 36864
#define CD 192
#define NH 6
#define HDIM 32
#define HIDD 768

typedef unsigned short u16;
typedef __attribute__((ext_vector_type(8))) short bf16x8;
typedef __attribute__((ext_vector_type(4))) float f32x4;
typedef __attribute__((ext_vector_type(8))) _Float16 f16x8;
typedef __attribute__((ext_vector_type(2))) __fp16 fp16x2;

__device__ __forceinline__ float gelu_f(float x) {
  return 0.5f * x * (1.0f + erff(x * 0.70710678118654752f));
}
__device__ __forceinline__ u16 f2b(float f) {
  union { float f; unsigned u; } v; v.f = f;
  unsigned r = v.u + 0x7fff + ((v.u >> 16) & 1);   // RNE
  return (u16)(r >> 16);
}
__device__ __forceinline__ float b2f(u16 b) {
  union { unsigned u; float f; } v; v.u = ((unsigned)b) << 16;
  return v.f;
}
// packed f32->f16 (RTZ), result as the raw 32-bit word
__device__ __forceinline__ unsigned pkrtz_u(float a, float b) {
  union { fp16x2 h; unsigned u; } cv;
  cv.h = __builtin_amdgcn_cvt_pkrtz(a, b);
  return cv.u;
}

// ---------- fused LayerNorm + transpose: fp32 CM in -> bf16 TM out ----------
__global__ __launch_bounds__(256)
void lnt_kernel(const float* __restrict__ in, const float* __restrict__ g,
                const float* __restrict__ b, u16* __restrict__ outTM)
{
  __shared__ float tile[64][193];
  __shared__ float red[64][8];
  __shared__ float2 stat2[64];
  __shared__ float gb[384];
  const int tid = threadIdx.x;
  const int part = tid >> 6, tk = tid & 63;
  const int tok = blockIdx.x * 64 + tk;
  if (tid < 192) { gb[tid] = g[tid]; gb[192 + tid] = b[tid]; }
  float s = 0.f, sq = 0.f;
  for (int c = part * 48; c < part * 48 + 48; ++c) {
    float v = in[(size_t)c * HW + tok];
    tile[tk][c] = v; s += v; sq += v * v;
  }
  red[tk][part] = s; red[tk][4 + part] = sq;
  __syncthreads();
  if (tid < 64) {
    float ss = red[tid][0] + red[tid][1] + red[tid][2] + red[tid][3];
    float qq = red[tid][4] + red[tid][5] + red[tid][6] + red[tid][7];
    float m = ss * (1.0f / CD);
    float var = fmaxf(qq * (1.0f / CD) - m * m, 0.f);
    stat2[tid] = make_float2(m, rsqrtf(var + 1e-5f));
  }
  __syncthreads();
  unsigned* op = (unsigned*)outTM + (size_t)blockIdx.x * 6144;
  #pragma unroll
  for (int r = 0; r < 24; ++r) {
    int idx = tid + r * 256;
    int tok2 = idx / 96, dc = idx - tok2 * 96;
    float2 st = stat2[tok2];
    int c = dc * 2;
    float v0 = (tile[tok2][c] - st.x) * st.y * gb[c] + gb[192 + c];
    float v1 = (tile[tok2][c + 1] - st.x) * st.y * gb[c + 1] + gb[192 + c + 1];
    op[idx] = (unsigned)f2b(v0) | ((unsigned)f2b(v1) << 16);
  }
}

// ---------- weight prep: fp32 [K][N] -> bf16 [N][K] ----------
__global__ __launch_bounds__(256)
void wtrans_kernel(const float* __restrict__ in, u16* __restrict__ out, int K, int N)
{
  __shared__ float ls[32][33];
  const int k0 = blockIdx.x * 32, n0 = blockIdx.y * 32;
  const int t = threadIdx.x;
  #pragma unroll
  for (int r = 0; r < 4; ++r) {
    int idx = t + r * 256;
    int k = idx >> 5, n = idx & 31;
    ls[k][n] = in[(size_t)(k0 + k) * N + n0 + n];
  }
  __syncthreads();
  #pragma unroll
  for (int r = 0; r < 4; ++r) {
    int idx = t + r * 256;
    int n = idx >> 5, k = idx & 31;
    out[(size_t)(n0 + n) * K + k0 + k] = f2b(ls[k][n]);
  }
}

// 4 square 192x192 weights in one launch
__global__ __launch_bounds__(256)
void wtrans4_kernel(const float* __restrict__ w0, const float* __restrict__ w1,
                    const float* __restrict__ w2, const float* __restrict__ w3,
                    u16* __restrict__ out)
{
  __shared__ float ls[32][33];
  const int z = blockIdx.z;
  const float* in = (z == 0) ? w0 : (z == 1 ? w1 : (z == 2 ? w2 : w3));
  u16* op = out + (size_t)z * CD * CD;
  const int k0 = blockIdx.x * 32, n0 = blockIdx.y * 32;
  const int t = threadIdx.x;
  #pragma unroll
  for (int r = 0; r < 4; ++r) {
    int idx = t + r * 256;
    int k = idx >> 5, n = idx & 31;
    ls[k][n] = in[(size_t)(k0 + k) * CD + n0 + n];
  }
  __syncthreads();
  #pragma unroll
  for (int r = 0; r < 4; ++r) {
    int idx = t + r * 256;
    int n = idx >> 5, k = idx & 31;
    op[(size_t)(n0 + n) * CD + k0 + k] = f2b(ls[k][n]);
  }
}

// ---------- bf16 MFMA GEMM: D[m][n] = A[m][:].Wt[n][:] + epilogue ----------
// MODE 0: QKV  -> bf16 CM out, +bias, q-segment scaled
// MODE 1: PROJ -> fp32 CM out, +bias +aux (fp32 CM)
// MODE 2: FC1  -> bf16 CM out, +bias, GELU
template<int MODE>
__global__ __launch_bounds__(256, 4)
void mgemm_kernel(const u16* __restrict__ A,
                  const u16* __restrict__ W0, const u16* __restrict__ W1, const u16* __restrict__ W2,
                  const float* __restrict__ b0, const float* __restrict__ b1, const float* __restrict__ b2,
                  const float* __restrict__ aux, void* __restrict__ outv,
                  int K, int segN)
{
  const int n0 = blockIdx.x * 64;
  const int m0 = blockIdx.y * 128;
  const int seg = n0 / segN;
  const u16* Wp = (seg == 0) ? W0 : (seg == 1 ? W1 : W2);
  const float* biasp = (seg == 0) ? b0 : (seg == 1 ? b1 : b2);
  const int nl0 = n0 - seg * segN;

  __shared__ u16 As[128 * 32];
  __shared__ u16 Bs[64 * 32];

  const int tid = threadIdx.x;
  const int lane = tid & 63, wave = tid >> 6;
  const int wm = (wave >> 1) * 64, wn = (wave & 1) * 32;
  const int fm = lane & 15, fq = lane >> 4;
  const int ar = tid >> 2, akq = tid & 3;

  f32x4 acc[4][2];
  #pragma unroll
  for (int i = 0; i < 4; ++i) { acc[i][0] = (f32x4)(0.f); acc[i][1] = (f32x4)(0.f); }

  uint4 rA0, rA1, rB, nA0, nA1, nB;
  rA0 = *(const uint4*)(A + (size_t)(m0 + ar) * K + akq * 8);
  rA1 = *(const uint4*)(A + (size_t)(m0 + ar + 64) * K + akq * 8);
  rB  = *(const uint4*)(Wp + (size_t)(nl0 + ar) * K + akq * 8);

  for (int k0 = 0; k0 < K; k0 += 32) {
    *(uint4*)(&As[ar * 32 + akq * 8]) = rA0;
    *(uint4*)(&As[(ar + 64) * 32 + akq * 8]) = rA1;
    *(uint4*)(&Bs[ar * 32 + akq * 8]) = rB;
    __syncthreads();
    const int kn = (k0 + 32 < K) ? k0 + 32 : k0;
    nA0 = *(const uint4*)(A + (size_t)(m0 + ar) * K + kn + akq * 8);
    nA1 = *(const uint4*)(A + (size_t)(m0 + ar + 64) * K + kn + akq * 8);
    nB  = *(const uint4*)(Wp + (size_t)(nl0 + ar) * K + kn + akq * 8);
    bf16x8 af[4], bf[2];
    #pragma unroll
    for (int mt = 0; mt < 4; ++mt)
      af[mt] = *(const bf16x8*)(&As[(wm + mt * 16 + fm) * 32 + fq * 8]);
    #pragma unroll
    for (int nt = 0; nt < 2; ++nt)
      bf[nt] = *(const bf16x8*)(&Bs[(wn + nt * 16 + fm) * 32 + fq * 8]);
    #pragma unroll
    for (int mt = 0; mt < 4; ++mt)
      #pragma unroll
      for (int nt = 0; nt < 2; ++nt)
        acc[mt][nt] = __builtin_amdgcn_mfma_f32_16x16x32_bf16(af[mt], bf[nt], acc[mt][nt], 0, 0, 0);
    __syncthreads();
    rA0 = nA0; rA1 = nA1; rB = nB;
  }

  #pragma unroll
  for (int nt = 0; nt < 2; ++nt) {
    const int n = n0 + wn + nt * 16 + fm;
    const float bia = biasp[nl0 + wn + nt * 16 + fm];
    #pragma unroll
    for (int mt = 0; mt < 4; ++mt) {
      const int mb = m0 + wm + mt * 16 + fq * 4;
      float o[4];
      #pragma unroll
      for (int r = 0; r < 4; ++r) o[r] = acc[mt][nt][r] + bia;
      if (MODE == 0) {
        const float sc = (seg == 0) ? 0.17677669529663689f : 1.0f;  // q pre-scaled by hd^-0.5
        u16 h0 = f2b(o[0] * sc), h1 = f2b(o[1] * sc), h2 = f2b(o[2] * sc), h3 = f2b(o[3] * sc);
        uint2 pk = make_uint2((unsigned)h0 | ((unsigned)h1 << 16), (unsigned)h2 | ((unsigned)h3 << 16));
        *(uint2*)((u16*)outv + (size_t)n * HW + mb) = pk;
      } else if (MODE == 1) {
        const float4 ax = *(const float4*)(aux + (size_t)n * HW + mb);
        *(float4*)((float*)outv + (size_t)n * HW + mb) =
            make_float4(o[0] + ax.x, o[1] + ax.y, o[2] + ax.z, o[3] + ax.w);
      } else if (MODE == 2) {
        u16 h0 = f2b(gelu_f(o[0])), h1 = f2b(gelu_f(o[1]));
        u16 h2 = f2b(gelu_f(o[2])), h3 = f2b(gelu_f(o[3]));
        uint2 pk = make_uint2((unsigned)h0 | ((unsigned)h1 << 16), (unsigned)h2 | ((unsigned)h3 << 16));
        *(uint2*)((u16*)outv + (size_t)n * HW + mb) = pk;
      }
    }
  }
}

// ---------- FC2: A read column-major (y2 CM [768][HW]) with LDS transpose
// staging; fp32 TM out = A.W^T + bias + aux. Kills the trans_kernel pass. ----
__global__ __launch_bounds__(256, 4)
void fc2_kernel(const u16* __restrict__ A,    // y2 CM [768][HW]
                const u16* __restrict__ W,    // wf2t [192][768]
                const float* __restrict__ bias,
                const float* __restrict__ aux, // x2 fp32 CM [192][HW]
                float* __restrict__ outTM)     // fp32 TM [HW][192]
{
  const int n0 = blockIdx.x * 64;
  const int m0 = blockIdx.y * 128;

  __shared__ u16 As2[32 * 130];   // [k][m], pitch 130 u16 -> conflict-free frag reads
  __shared__ u16 Bs[64 * 32];

  const int tid = threadIdx.x;
  const int lane = tid & 63, wave = tid >> 6;
  const int wm = (wave >> 1) * 64, wn = (wave & 1) * 32;
  const int fm = lane & 15, fq = lane >> 4;
  const int kt = tid >> 4;          // 0..15 (k row within half-step)
  const int m8 = (tid & 15) * 8;    // 0..120
  const int br = tid >> 2, bkq = tid & 3;

  f32x4 acc[4][2];
  #pragma unroll
  for (int i = 0; i < 4; ++i) { acc[i][0] = (f32x4)(0.f); acc[i][1] = (f32x4)(0.f); }

  uint4 rA0, rA1, rB, nA0, nA1, nB;
  rA0 = *(const uint4*)(A + (size_t)kt * HW + m0 + m8);
  rA1 = *(const uint4*)(A + (size_t)(kt + 16) * HW + m0 + m8);
  rB  = *(const uint4*)(W + (size_t)(n0 + br) * HIDD + bkq * 8);

  for (int k0 = 0; k0 < HIDD; k0 += 32) {
    // stage A transposed-by-layout: As2[k][m] via 4x b32 each (2-way max conflict)
    #pragma unroll
    for (int i = 0; i < 4; ++i)
      *(unsigned*)&As2[kt * 130 + m8 + 2 * i] = ((const unsigned*)&rA0)[i];
    #pragma unroll
    for (int i = 0; i < 4; ++i)
      *(unsigned*)&As2[(kt + 16) * 130 + m8 + 2 * i] = ((const unsigned*)&rA1)[i];
    *(uint4*)(&Bs[br * 32 + bkq * 8]) = rB;
    __syncthreads();
    const int kn = (k0 + 32 < HIDD) ? k0 + 32 : k0;
    nA0 = *(const uint4*)(A + (size_t)(kn + kt) * HW + m0 + m8);
    nA1 = *(const uint4*)(A + (size_t)(kn + kt + 16) * HW + m0 + m8);
    nB  = *(const uint4*)(W + (size_t)(n0 + br) * HIDD + kn + bkq * 8);
    // A fragments via 8 scalar u16 reads (conflict-free: fq-groups hit disjoint
    // 8-bank windows since 520%32==8, 65%32==1)
    bf16x8 af[4];
    #pragma unroll
    for (int mt = 0; mt < 4; ++mt) {
      union { bf16x8 v; u16 h[8]; } t;
      const int m = wm + mt * 16 + fm;
      #pragma unroll
      for (int e = 0; e < 8; ++e)
        t.h[e] = As2[(fq * 8 + e) * 130 + m];
      af[mt] = t.v;
    }
    bf16x8 bf[2];
    #pragma unroll
    for (int nt = 0; nt < 2; ++nt)
      bf[nt] = *(const bf16x8*)(&Bs[(wn + nt * 16 + fm) * 32 + fq * 8]);
    #pragma unroll
    for (int mt = 0; mt < 4; ++mt)
      #pragma unroll
      for (int nt = 0; nt < 2; ++nt)
        acc[mt][nt] = __builtin_amdgcn_mfma_f32_16x16x32_bf16(af[mt], bf[nt], acc[mt][nt], 0, 0, 0);
    __syncthreads();
    rA0 = nA0; rA1 = nA1; rB = nB;
  }

  #pragma unroll
  for (int nt = 0; nt < 2; ++nt) {
    const int n = n0 + wn + nt * 16 + fm;
    const float bia = bias[n0 + wn + nt * 16 + fm];
    #pragma unroll
    for (int mt = 0; mt < 4; ++mt) {
      const int mb = m0 + wm + mt * 16 + fq * 4;
      const float4 ax = *(const float4*)(aux + (size_t)n * HW + mb);
      outTM[(size_t)(mb + 0) * CD + n] = acc[mt][nt][0] + bia + ax.x;
      outTM[(size_t)(mb + 1) * CD + n] = acc[mt][nt][1] + bia + ax.y;
      outTM[(size_t)(mb + 2) * CD + n] = acc[mt][nt][2] + bia + ax.z;
      outTM[(size_t)(mb + 3) * CD + n] = acc[mt][nt][3] + bia + ax.w;
    }
  }
}

// ---------- depthwise 5x5 conv + bias + exact GELU (+optional residual) ----------
template<bool ADD>
__global__ __launch_bounds__(256)
void dwconv_kernel(const u16* __restrict__ in, const float* __restrict__ w,
                   const float* __restrict__ bias, u16* __restrict__ out)
{
  const int plane = blockIdx.z;
  const int bx = blockIdx.x * 64, by = blockIdx.y * 4;
  __shared__ float tile[8][68];
  __shared__ float ws[26];
  const int tid = threadIdx.x;
  if (tid < 26) ws[tid] = (tid < 25) ? w[plane * 25 + tid] : bias[plane];
  const u16* ip = in + (size_t)plane * HW;
  for (int e = tid; e < 544; e += 256) {
    int r = e / 68, cc = e - r * 68;
    int gy = by + r - 2, gx = bx + cc - 2;
    tile[r][cc] = (gy >= 0 && gy < 192 && gx >= 0 && gx < 192) ? b2f(ip[gy * 192 + gx]) : 0.f;
  }
  __syncthreads();
  const int tx = tid & 63, ty = tid >> 6;
  float acc = 0.f;
  #pragma unroll
  for (int dy = 0; dy < 5; ++dy)
    #pragma unroll
    for (int dx = 0; dx < 5; ++dx)
      acc = fmaf(tile[ty + dy][tx + dx], ws[dy * 5 + dx], acc);
  float v = gelu_f(acc + ws[25]);
  if (ADD) v += tile[ty + 2][tx + 2];
  out[(size_t)plane * HW + (by + ty) * 192 + bx + tx] = f2b(v);
}

// ---------- fused window attention v5b (reverted; measured 258 us) ----------
// 512 thr, 3 blocks/CU (LDS 52,356 B), f16 V + single f16 MFMA for P.V,
// pfa loads software-pipelined (issue end-of-C), 19-bit radix select.
__global__ __launch_bounds__(512, 6)
void attn_kernel(const u16* __restrict__ qg, const u16* __restrict__ kg,
                 const u16* __restrict__ vg, const u16* __restrict__ vlg,
                 const float* __restrict__ pfa_v, const int* __restrict__ pfa_i,
                 const int* __restrict__ rpi, const float* __restrict__ rpb_t,
                 u16* __restrict__ attn_out)
{
  const int h = blockIdx.x;
  const int win = blockIdx.y;
  const int wy = (win / 12) * 16;
  const int wx = (win - (win / 12) * 12) * 16;
  const size_t hb = (size_t)h * HDIM * HW;

  __shared__ float Sb[32][262];   // scores / P rows, stride 1048B   33536 B (aliased as K staging [256][40] u16)
  __shared__ u16 vT[32][264];     // V^T [d][j] f16 bits             16896 B
  __shared__ u16 rpb_h[962];      // rpb bf16                         1924 B
                                  // total 52356 -> 52736 rounded -> 3 blk/CU

  const int tid = threadIdx.x;
  const int lane = tid & 63, wave = tid >> 6;
  const int fm = lane & 15, fq = lane >> 4;

  for (int r = tid; r < 961; r += 512) rpb_h[r] = f2b(rpb_t[r * 6 + h]);

  // stage K [256][40] u16 into Sb bytes, V^T (f16 bits) into vT
  u16* kst = (u16*)&Sb[0][0];
  #pragma unroll
  for (int r = 0; r < 8; ++r) {
    int idx = tid + r * 512;
    int d = idx >> 7, jp = idx & 127, j = jp * 2;
    int pg = (wy + (j >> 4)) * 192 + (wx + (j & 15));
    ushort2 kv = *(const ushort2*)(kg + hb + (size_t)d * HW + pg);
    kst[j * 40 + d] = kv.x; kst[(j + 1) * 40 + d] = kv.y;
    ushort2 vv = *(const ushort2*)(vg + hb + (size_t)d * HW + pg);
    *(unsigned*)&vT[d][j] = pkrtz_u(b2f(vv.x), b2f(vv.y));
  }
  __syncthreads();

  // hoist K fragments (pass-invariant) into 16 VGPRs
  bf16x8 kf[4];
  #pragma unroll
  for (int t = 0; t < 4; ++t) {
    const int j0 = ((wave >> 1) * 4 + t) * 16;
    kf[t] = *(const bf16x8*)&kst[(j0 + fm) * 40 + fq * 8];
  }
  // (pass-0 top barrier orders these reads before Sb score writes)

  const size_t wb = ((size_t)win * NH + h) * 256;
  const unsigned long long lmlt = (1ull << lane) - 1ull;
  const unsigned KMASK = 0xFFFFF800u;   // 21-bit selection key (bits 31..11)

  // preload pass-0 pfa
  int pj1[4], pj2[4]; float pv1[4], pv2[4];
  #pragma unroll
  for (int u = 0; u < 4; ++u) {
    const size_t base = (wb + (size_t)(u * 8 + wave)) * 128;
    pj1[u] = pfa_i[base + lane];  pj2[u] = pfa_i[base + 64 + lane];
    pv1[u] = pfa_v[base + lane];  pv2[u] = pfa_v[base + 64 + lane];
  }

  for (int pass = 0; pass < 8; ++pass) {
    // Q fragment straight from global (q already scaled by hd^-0.5)
    union { bf16x8 v; u16 hh[8]; } aqu;
    {
      const int pgq = (wy + pass * 2 + (wave & 1)) * 192 + wx + fm;
      #pragma unroll
      for (int e = 0; e < 8; ++e)
        aqu.hh[e] = qg[hb + (size_t)(fq * 8 + e) * HW + pgq];
    }
    // vl prefetch for the D epilogue (wave<4 only)
    float vlv[4];
    if (wave < 4) {
      const int mt = wave & 1, nt = wave >> 1;
      const int pgo = (wy + pass * 2 + nt) * 192 + wx + fm;
      const int d0 = mt * 16 + fq * 4;
      #pragma unroll
      for (int e = 0; e < 4; ++e)
        vlv[e] = b2f(vlg[hb + (size_t)(d0 + e) * HW + pgo]);
    }
    __syncthreads();   // prev-pass D reads of Sb done (and pass-0 kf reads)

    // rpi prefetch for this pass (covered by B)
    int rbi1[4], rbi2[4];
    #pragma unroll
    for (int u = 0; u < 4; ++u) {
      const int i = pass * 32 + u * 8 + wave;
      rbi1[u] = rpi[i * 256 + pj1[u]];
      rbi2[u] = rpi[i * 256 + pj2[u]];
    }

    // B: scores via MFMA -> Sb
    #pragma unroll
    for (int t = 0; t < 4; ++t) {
      f32x4 c = __builtin_amdgcn_mfma_f32_16x16x32_bf16(aqu.v, kf[t], (f32x4)(0.f), 0, 0, 0);
      const int col = ((wave >> 1) * 4 + t) * 16 + fm;
      const int rowb = (wave & 1) * 16 + fq * 4;
      Sb[rowb + 0][col] = c[0]; Sb[rowb + 1][col] = c[1];
      Sb[rowb + 2][col] = c[2]; Sb[rowb + 3][col] = c[3];
    }
    __syncthreads();

    // C: batched 4-query phases (each wave owns rows u*8+wave)
    float s1[4], s2[4];
    #pragma unroll
    for (int u = 0; u < 4; ++u) {
      const int iq = u * 8 + wave;
      s1[u] = Sb[iq][pj1[u]] + b2f(rpb_h[rbi1[u]]);
      s2[u] = Sb[iq][pj2[u]] + b2f(rpb_h[rbi2[u]]);
    }
    // zero own rows (scores consumed); becomes the P scatter target
    {
      const float2 z2 = make_float2(0.f, 0.f);
      #pragma unroll
      for (int u = 0; u < 4; ++u) {
        const int iq = u * 8 + wave;
        *(float2*)&Sb[iq][lane * 4]     = z2;
        *(float2*)&Sb[iq][lane * 4 + 2] = z2;
      }
    }
    float mx[4];
    #pragma unroll
    for (int u = 0; u < 4; ++u) mx[u] = fmaxf(s1[u], s2[u]);
    #pragma unroll
    for (int o = 32; o > 0; o >>= 1)
      #pragma unroll
      for (int u = 0; u < 4; ++u) mx[u] = fmaxf(mx[u], __shfl_xor(mx[u], o));
    float e1[4], e2[4], sA[4], sB[4];
    #pragma unroll
    for (int u = 0; u < 4; ++u) {
      e1[u] = expf(s1[u] - mx[u]); e2[u] = expf(s2[u] - mx[u]);
      sA[u] = e1[u] + e2[u];
      sB[u] = e1[u] * pv1[u] + e2[u] * pv2[u];
    }
    #pragma unroll
    for (int o = 32; o > 0; o >>= 1)
      #pragma unroll
      for (int u = 0; u < 4; ++u) { sA[u] += __shfl_xor(sA[u], o); sB[u] += __shfl_xor(sB[u], o); }
    unsigned ub1[4], ub2[4]; float a1[4], a2[4];
    #pragma unroll
    for (int u = 0; u < 4; ++u) {
      const float rs = 1.0f / sA[u];
      const float rden = 1.0f / (sB[u] * rs + 1e-10f);
      a1[u] = (e1[u] * rs * pv1[u] + 1e-10f) * rden;
      a2[u] = (e2[u] * rs * pv2[u] + 1e-10f) * rden;
      ub1[u] = __float_as_uint(a1[u]); ub2[u] = __float_as_uint(a2[u]);
    }
    // branchless batched radix select on 19-bit key (a < 2 => bit30 == 0)
    unsigned thr[4] = {0u, 0u, 0u, 0u};
    #pragma unroll 1
    for (int bit = 29; bit >= 11; --bit) {
      #pragma unroll
      for (int u = 0; u < 4; ++u) {
        const unsigned cand = thr[u] | (1u << bit);
        const int cnt = (int)__popcll(__ballot(ub1[u] >= cand)) +
                        (int)__popcll(__ballot(ub2[u] >= cand));
        thr[u] = (cnt >= 64) ? cand : thr[u];
      }
    }
    // tie-break on masked key (position order, matches jax top_k) and scatter-sum
    #pragma unroll
    for (int u = 0; u < 4; ++u) {
      const int iq = u * 8 + wave;
      const unsigned kb1 = ub1[u] & KMASK, kb2 = ub2[u] & KMASK;
      const bool gt1 = kb1 > thr[u], gt2 = kb2 > thr[u];
      const bool eq1 = kb1 == thr[u], eq2 = kb2 == thr[u];
      const unsigned long long meq1 = __ballot(eq1), meq2 = __ballot(eq2);
      const int need = 64 - (int)__popcll(__ballot(gt1)) - (int)__popcll(__ballot(gt2));
      const bool sel1 = gt1 || (eq1 && (int)__popcll(meq1 & lmlt) < need);
      const bool sel2 = gt2 || (eq2 && ((int)__popcll(meq1) + (int)__popcll(meq2 & lmlt)) < need);
      if (sel1) atomicAdd(&Sb[iq][pj1[u]], a1[u]);
      if (sel2) atomicAdd(&Sb[iq][pj2[u]], a2[u]);
    }
    // issue next pass's pfa loads (in flight across D + barrier + B)
    int npj1[4], npj2[4]; float npv1[4], npv2[4];
    {
      const int pnext = (pass + 1) & 7;
      #pragma unroll
      for (int u = 0; u < 4; ++u) {
        const size_t base = (wb + (size_t)(pnext * 32 + u * 8 + wave)) * 128;
        npj1[u] = pfa_i[base + lane];  npj2[u] = pfa_i[base + 64 + lane];
        npv1[u] = pfa_v[base + lane];  npv2[u] = pfa_v[base + 64 + lane];
      }
    }
    __syncthreads();

    // D: O = V^T (32d x 256j) . P^T (256j x 32i), single f16 MFMA per k0
    if (wave < 4) {
      const int mt = wave & 1, nt = wave >> 1;
      f32x4 acc = (f32x4)(0.f);
      #pragma unroll
      for (int k0 = 0; k0 < 8; ++k0) {
        const f16x8 av = *(const f16x8*)&vT[mt * 16 + fm][k0 * 32 + fq * 8];
        const float* pr = &Sb[nt * 16 + fm][k0 * 32 + fq * 8];
        const float2 p01 = *(const float2*)(pr + 0);
        const float2 p23 = *(const float2*)(pr + 2);
        const float2 p45 = *(const float2*)(pr + 4);
        const float2 p67 = *(const float2*)(pr + 6);
        union { f16x8 v; unsigned q[4]; } bp;
        bp.q[0] = pkrtz_u(p01.x, p01.y);
        bp.q[1] = pkrtz_u(p23.x, p23.y);
        bp.q[2] = pkrtz_u(p45.x, p45.y);
        bp.q[3] = pkrtz_u(p67.x, p67.y);
        acc = __builtin_amdgcn_mfma_f32_16x16x32_f16(av, bp.v, acc, 0, 0, 0);
      }
      // epilogue: D row = d-within-tile, col = i-within-tile
      const int pgo = (wy + pass * 2 + nt) * 192 + wx + fm;
      const int d0 = mt * 16 + fq * 4;
      const float r0 = acc[0] + vlv[0];
      const float r1 = acc[1] + vlv[1];
      const float r2 = acc[2] + vlv[2];
      const float r3 = acc[3] + vlv[3];
      const unsigned o01 = (unsigned)f2b(r0) | ((unsigned)f2b(r1) << 16);
      const unsigned o23 = (unsigned)f2b(r2) | ((unsigned)f2b(r3) << 16);
      *(uint2*)(attn_out + (size_t)pgo * CD + h * HDIM + d0) = make_uint2(o01, o23);
    }
    // rotate pfa pipeline
    #pragma unroll
    for (int u = 0; u < 4; ++u) {
      pj1[u] = npj1[u]; pj2[u] = npj2[u];
      pv1[u] = npv1[u]; pv2[u] = npv2[u];
    }
  }
}

// ---------- launch ----------
extern "C" void kernel_launch(void* const* d_in, const int* in_sizes, int n_in,
                              void* d_out, int out_size, void* d_ws, size_t ws_size,
                              hipStream_t stream)
{
  (void)in_sizes; (void)n_in; (void)out_size; (void)ws_size;
  const float* features = (const float*)d_in[0];
  const float* pfa_v    = (const float*)d_in[1];
  const int*   pfa_i    = (const int*)d_in[2];
  const int*   rpi      = (const int*)d_in[3];
  const float* ln1_g    = (const float*)d_in[4];
  const float* ln1_b    = (const float*)d_in[5];
  const float* Wq_w     = (const float*)d_in[6];
  const float* Wq_b     = (const float*)d_in[7];
  const float* Wk_w     = (const float*)d_in[8];
  const float* Wk_b     = (const float*)d_in[9];
  const float* Wv_w     = (const float*)d_in[10];
  const float* Wv_b     = (const float*)d_in[11];
  const float* lepe_w   = (const float*)d_in[12];
  const float* lepe_b   = (const float*)d_in[13];
  const float* rpb_t    = (const float*)d_in[14];
  const float* proj_w   = (const float*)d_in[15];
  const float* proj_b   = (const float*)d_in[16];
  const float* ln2_g    = (const float*)d_in[17];
  const float* ln2_b    = (const float*)d_in[18];
  const float* fc1_w    = (const float*)d_in[19];
  const float* fc1_b    = (const float*)d_in[20];
  const float* dw_w     = (const float*)d_in[21];
  const float* dw_b     = (const float*)d_in[22];
  const float* fc2_w    = (const float*)d_in[23];
  const float* fc2_b    = (const float*)d_in[24];

  char* ws = (char*)d_ws;
  const size_t S  = (size_t)HW * CD;
  const size_t SB = S * 4;
  u16*   xnt    = (u16*)(ws);                         // [0, 0.5SB) bf16 TM
  u16*   qkvb   = (u16*)(ws + SB / 2);                // [0.5SB, 2SB) bf16 CM (q scaled, k, v)
  u16*   q_ = qkvb; u16* k_ = qkvb + S; u16* v_ = qkvb + 2 * S;
  u16*   vl     = (u16*)(ws + 2 * SB);                // [2SB, 2.5SB)
  u16*   attn_o = (u16*)(ws + 2 * SB + SB / 2);       // [2.5SB, 3SB) bf16 TM
  float* x2     = (float*)(ws + 3 * SB);              // [3SB, 4SB) fp32 CM, live to end
  u16*   xn2t   = (u16*)(ws + 4 * SB);                // [4SB, 4.5SB)
  u16*   y_     = (u16*)(ws + 4 * SB + SB / 2);       // [4.5SB, 6.5SB) bf16 CM 768xHW
  u16*   y2_    = (u16*)(ws + 6 * SB + SB / 2);       // [6.5SB, 8.5SB)
  u16*   wqt  = (u16*)(ws + 8 * SB + SB / 2);
  u16*   wkt  = wqt + 36864;
  u16*   wvt  = wkt + 36864;
  u16*   wpt  = wvt + 36864;
  u16*   wf1t = wpt + 36864;      // [768][192]
  u16*   wf2t = wf1t + 147456;    // [192][768]
  float* out = (float*)d_out;

  // 0) weight prep
  wtrans4_kernel<<<dim3(6, 6, 4), 256, 0, stream>>>(Wq_w, Wk_w, Wv_w, proj_w, wqt);
  wtrans_kernel<<<dim3(6, 24), 256, 0, stream>>>(fc1_w, wf1t, 192, 768);
  wtrans_kernel<<<dim3(24, 6), 256, 0, stream>>>(fc2_w, wf2t, 768, 192);
  // 1) LN1 fused transpose -> bf16 TM
  lnt_kernel<<<dim3(HW / 64), 256, 0, stream>>>(features, ln1_g, ln1_b, xnt);
  // 2) QKV MFMA -> bf16 CM (q scaled)
  mgemm_kernel<0><<<dim3(9, HW / 128), 256, 0, stream>>>(xnt, wqt, wkt, wvt, Wq_b, Wk_b, Wv_b,
                                                         nullptr, qkvb, 192, 192);
  // 3) LePE dwconv on v (bf16)
  dwconv_kernel<false><<<dim3(3, 48, 192), 256, 0, stream>>>(v_, lepe_w, lepe_b, vl);
  // 4) window attention -> bf16 TM
  attn_kernel<<<dim3(6, 144), 512, 0, stream>>>(q_, k_, v_, vl, pfa_v, pfa_i, rpi, rpb_t, attn_o);
  // 5) proj + shortcut -> fp32 CM x2
  mgemm_kernel<1><<<dim3(3, HW / 128), 256, 0, stream>>>(attn_o, wpt, wpt, wpt, proj_b, proj_b, proj_b,
                                                         features, x2, 192, 1 << 30);
  // 6) LN2 fused transpose -> bf16 TM
  lnt_kernel<<<dim3(HW / 64), 256, 0, stream>>>(x2, ln2_g, ln2_b, xn2t);
  // 7) fc1 + GELU -> bf16 CM y
  mgemm_kernel<2><<<dim3(12, HW / 128), 256, 0, stream>>>(xn2t, wf1t, wf1t, wf1t, fc1_b, fc1_b, fc1_b,
                                                          nullptr, y_, 192, 1 << 30);
  // 8) y2 = y + gelu(dwconv(y)+b) -> bf16 CM
  dwconv_kernel<true><<<dim3(3, 48, 768), 256, 0, stream>>>(y_, dw_w, dw_b, y2_);
  // 9) fc2 reads y2 CM directly (transpose-staged) + x2 residual -> fp32 TM out
  fc2_kernel<<<dim3(3, HW / 128), 256, 0, stream>>>(y2_, wf2t, fc2_b, x2, out);
}

// Round 8
// 734.830 us; speedup vs baseline: 1.2647x; 1.0586x over previous
//
#include <hip/hip_runtime.h>
#include <math.h>

#define HW 36864
#define CD 192
#define NH 6
#define HDIM 32
#define HIDD 768

typedef unsigned short u16;
typedef __attribute__((ext_vector_type(8))) short bf16x8;
typedef __attribute__((ext_vector_type(4))) float f32x4;
typedef __attribute__((ext_vector_type(8))) _Float16 f16x8;
typedef __attribute__((ext_vector_type(2))) __fp16 fp16x2;

__device__ __forceinline__ float gelu_f(float x) {
  return 0.5f * x * (1.0f + erff(x * 0.70710678118654752f));
}
__device__ __forceinline__ u16 f2b(float f) {
  union { float f; unsigned u; } v; v.f = f;
  unsigned r = v.u + 0x7fff + ((v.u >> 16) & 1);   // RNE
  return (u16)(r >> 16);
}
__device__ __forceinline__ float b2f(u16 b) {
  union { unsigned u; float f; } v; v.u = ((unsigned)b) << 16;
  return v.f;
}
// packed f32->f16 (RTZ), result as the raw 32-bit word
__device__ __forceinline__ unsigned pkrtz_u(float a, float b) {
  union { fp16x2 h; unsigned u; } cv;
  cv.h = __builtin_amdgcn_cvt_pkrtz(a, b);
  return cv.u;
}

// ---- DPP wave64 reductions (no LDS traffic; rocPRIM CDNA pattern) ----
// row_shr:N = 0x110+N, row_bcast15 = 0x142, row_bcast31 = 0x143
template<int CTRL>
__device__ __forceinline__ float dpp_add(float v) {
  int t = __builtin_amdgcn_update_dpp(0, __float_as_int(v), CTRL, 0xf, 0xf, false);
  return v + __int_as_float(t);
}
template<int CTRL>
__device__ __forceinline__ float dpp_max(float v) {
  int t = __builtin_amdgcn_update_dpp(__float_as_int(v), __float_as_int(v), CTRL, 0xf, 0xf, false);
  return fmaxf(v, __int_as_float(t));
}
__device__ __forceinline__ float wave_sum(float v) {
  v = dpp_add<0x111>(v); v = dpp_add<0x112>(v);
  v = dpp_add<0x114>(v); v = dpp_add<0x118>(v);
  v = dpp_add<0x142>(v); v = dpp_add<0x143>(v);
  return __int_as_float(__builtin_amdgcn_readlane(__float_as_int(v), 63));
}
__device__ __forceinline__ float wave_max(float v) {
  v = dpp_max<0x111>(v); v = dpp_max<0x112>(v);
  v = dpp_max<0x114>(v); v = dpp_max<0x118>(v);
  v = dpp_max<0x142>(v); v = dpp_max<0x143>(v);
  return __int_as_float(__builtin_amdgcn_readlane(__float_as_int(v), 63));
}

// ---------- fused LayerNorm + transpose: fp32 CM in -> bf16 TM out ----------
__global__ __launch_bounds__(256)
void lnt_kernel(const float* __restrict__ in, const float* __restrict__ g,
                const float* __restrict__ b, u16* __restrict__ outTM)
{
  __shared__ float tile[64][193];
  __shared__ float red[64][8];
  __shared__ float2 stat2[64];
  __shared__ float gb[384];
  const int tid = threadIdx.x;
  const int part = tid >> 6, tk = tid & 63;
  const int tok = blockIdx.x * 64 + tk;
  if (tid < 192) { gb[tid] = g[tid]; gb[192 + tid] = b[tid]; }
  float s = 0.f, sq = 0.f;
  for (int c = part * 48; c < part * 48 + 48; ++c) {
    float v = in[(size_t)c * HW + tok];
    tile[tk][c] = v; s += v; sq += v * v;
  }
  red[tk][part] = s; red[tk][4 + part] = sq;
  __syncthreads();
  if (tid < 64) {
    float ss = red[tid][0] + red[tid][1] + red[tid][2] + red[tid][3];
    float qq = red[tid][4] + red[tid][5] + red[tid][6] + red[tid][7];
    float m = ss * (1.0f / CD);
    float var = fmaxf(qq * (1.0f / CD) - m * m, 0.f);
    stat2[tid] = make_float2(m, rsqrtf(var + 1e-5f));
  }
  __syncthreads();
  unsigned* op = (unsigned*)outTM + (size_t)blockIdx.x * 6144;
  #pragma unroll
  for (int r = 0; r < 24; ++r) {
    int idx = tid + r * 256;
    int tok2 = idx / 96, dc = idx - tok2 * 96;
    float2 st = stat2[tok2];
    int c = dc * 2;
    float v0 = (tile[tok2][c] - st.x) * st.y * gb[c] + gb[192 + c];
    float v1 = (tile[tok2][c + 1] - st.x) * st.y * gb[c + 1] + gb[192 + c + 1];
    op[idx] = (unsigned)f2b(v0) | ((unsigned)f2b(v1) << 16);
  }
}

// ---------- weight prep: fp32 [K][N] -> bf16 [N][K] ----------
__global__ __launch_bounds__(256)
void wtrans_kernel(const float* __restrict__ in, u16* __restrict__ out, int K, int N)
{
  __shared__ float ls[32][33];
  const int k0 = blockIdx.x * 32, n0 = blockIdx.y * 32;
  const int t = threadIdx.x;
  #pragma unroll
  for (int r = 0; r < 4; ++r) {
    int idx = t + r * 256;
    int k = idx >> 5, n = idx & 31;
    ls[k][n] = in[(size_t)(k0 + k) * N + n0 + n];
  }
  __syncthreads();
  #pragma unroll
  for (int r = 0; r < 4; ++r) {
    int idx = t + r * 256;
    int n = idx >> 5, k = idx & 31;
    out[(size_t)(n0 + n) * K + k0 + k] = f2b(ls[k][n]);
  }
}

// 4 square 192x192 weights in one launch
__global__ __launch_bounds__(256)
void wtrans4_kernel(const float* __restrict__ w0, const float* __restrict__ w1,
                    const float* __restrict__ w2, const float* __restrict__ w3,
                    u16* __restrict__ out)
{
  __shared__ float ls[32][33];
  const int z = blockIdx.z;
  const float* in = (z == 0) ? w0 : (z == 1 ? w1 : (z == 2 ? w2 : w3));
  u16* op = out + (size_t)z * CD * CD;
  const int k0 = blockIdx.x * 32, n0 = blockIdx.y * 32;
  const int t = threadIdx.x;
  #pragma unroll
  for (int r = 0; r < 4; ++r) {
    int idx = t + r * 256;
    int k = idx >> 5, n = idx & 31;
    ls[k][n] = in[(size_t)(k0 + k) * CD + n0 + n];
  }
  __syncthreads();
  #pragma unroll
  for (int r = 0; r < 4; ++r) {
    int idx = t + r * 256;
    int n = idx >> 5, k = idx & 31;
    op[(size_t)(n0 + n) * CD + k0 + k] = f2b(ls[k][n]);
  }
}

// ---------- bf16 MFMA GEMM: D[m][n] = A[m][:].Wt[n][:] + epilogue ----------
// MODE 0: QKV  -> bf16 CM out, +bias, q-segment scaled
// MODE 1: PROJ -> fp32 CM out, +bias +aux (fp32 CM)
// MODE 2: FC1  -> bf16 CM out, +bias, GELU
template<int MODE>
__global__ __launch_bounds__(256, 4)
void mgemm_kernel(const u16* __restrict__ A,
                  const u16* __restrict__ W0, const u16* __restrict__ W1, const u16* __restrict__ W2,
                  const float* __restrict__ b0, const float* __restrict__ b1, const float* __restrict__ b2,
                  const float* __restrict__ aux, void* __restrict__ outv,
                  int K, int segN)
{
  const int n0 = blockIdx.x * 64;
  const int m0 = blockIdx.y * 128;
  const int seg = n0 / segN;
  const u16* Wp = (seg == 0) ? W0 : (seg == 1 ? W1 : W2);
  const float* biasp = (seg == 0) ? b0 : (seg == 1 ? b1 : b2);
  const int nl0 = n0 - seg * segN;

  __shared__ u16 As[128 * 32];
  __shared__ u16 Bs[64 * 32];

  const int tid = threadIdx.x;
  const int lane = tid & 63, wave = tid >> 6;
  const int wm = (wave >> 1) * 64, wn = (wave & 1) * 32;
  const int fm = lane & 15, fq = lane >> 4;
  const int ar = tid >> 2, akq = tid & 3;

  f32x4 acc[4][2];
  #pragma unroll
  for (int i = 0; i < 4; ++i) { acc[i][0] = (f32x4)(0.f); acc[i][1] = (f32x4)(0.f); }

  uint4 rA0, rA1, rB, nA0, nA1, nB;
  rA0 = *(const uint4*)(A + (size_t)(m0 + ar) * K + akq * 8);
  rA1 = *(const uint4*)(A + (size_t)(m0 + ar + 64) * K + akq * 8);
  rB  = *(const uint4*)(Wp + (size_t)(nl0 + ar) * K + akq * 8);

  for (int k0 = 0; k0 < K; k0 += 32) {
    *(uint4*)(&As[ar * 32 + akq * 8]) = rA0;
    *(uint4*)(&As[(ar + 64) * 32 + akq * 8]) = rA1;
    *(uint4*)(&Bs[ar * 32 + akq * 8]) = rB;
    __syncthreads();
    const int kn = (k0 + 32 < K) ? k0 + 32 : k0;
    nA0 = *(const uint4*)(A + (size_t)(m0 + ar) * K + kn + akq * 8);
    nA1 = *(const uint4*)(A + (size_t)(m0 + ar + 64) * K + kn + akq * 8);
    nB  = *(const uint4*)(Wp + (size_t)(nl0 + ar) * K + kn + akq * 8);
    bf16x8 af[4], bf[2];
    #pragma unroll
    for (int mt = 0; mt < 4; ++mt)
      af[mt] = *(const bf16x8*)(&As[(wm + mt * 16 + fm) * 32 + fq * 8]);
    #pragma unroll
    for (int nt = 0; nt < 2; ++nt)
      bf[nt] = *(const bf16x8*)(&Bs[(wn + nt * 16 + fm) * 32 + fq * 8]);
    #pragma unroll
    for (int mt = 0; mt < 4; ++mt)
      #pragma unroll
      for (int nt = 0; nt < 2; ++nt)
        acc[mt][nt] = __builtin_amdgcn_mfma_f32_16x16x32_bf16(af[mt], bf[nt], acc[mt][nt], 0, 0, 0);
    __syncthreads();
    rA0 = nA0; rA1 = nA1; rB = nB;
  }

  #pragma unroll
  for (int nt = 0; nt < 2; ++nt) {
    const int n = n0 + wn + nt * 16 + fm;
    const float bia = biasp[nl0 + wn + nt * 16 + fm];
    #pragma unroll
    for (int mt = 0; mt < 4; ++mt) {
      const int mb = m0 + wm + mt * 16 + fq * 4;
      float o[4];
      #pragma unroll
      for (int r = 0; r < 4; ++r) o[r] = acc[mt][nt][r] + bia;
      if (MODE == 0) {
        const float sc = (seg == 0) ? 0.17677669529663689f : 1.0f;  // q pre-scaled by hd^-0.5
        u16 h0 = f2b(o[0] * sc), h1 = f2b(o[1] * sc), h2 = f2b(o[2] * sc), h3 = f2b(o[3] * sc);
        uint2 pk = make_uint2((unsigned)h0 | ((unsigned)h1 << 16), (unsigned)h2 | ((unsigned)h3 << 16));
        *(uint2*)((u16*)outv + (size_t)n * HW + mb) = pk;
      } else if (MODE == 1) {
        const float4 ax = *(const float4*)(aux + (size_t)n * HW + mb);
        *(float4*)((float*)outv + (size_t)n * HW + mb) =
            make_float4(o[0] + ax.x, o[1] + ax.y, o[2] + ax.z, o[3] + ax.w);
      } else if (MODE == 2) {
        u16 h0 = f2b(gelu_f(o[0])), h1 = f2b(gelu_f(o[1]));
        u16 h2 = f2b(gelu_f(o[2])), h3 = f2b(gelu_f(o[3]));
        uint2 pk = make_uint2((unsigned)h0 | ((unsigned)h1 << 16), (unsigned)h2 | ((unsigned)h3 << 16));
        *(uint2*)((u16*)outv + (size_t)n * HW + mb) = pk;
      }
    }
  }
}

// ---------- FC2: A read column-major (y2 CM [768][HW]) with LDS transpose
// staging; fp32 TM out = A.W^T + bias + aux. ----
__global__ __launch_bounds__(256, 4)
void fc2_kernel(const u16* __restrict__ A,    // y2 CM [768][HW]
                const u16* __restrict__ W,    // wf2t [192][768]
                const float* __restrict__ bias,
                const float* __restrict__ aux, // x2 fp32 CM [192][HW]
                float* __restrict__ outTM)     // fp32 TM [HW][192]
{
  const int n0 = blockIdx.x * 64;
  const int m0 = blockIdx.y * 128;

  __shared__ u16 As2[32 * 130];   // [k][m], pitch 130 u16 -> conflict-free frag reads
  __shared__ u16 Bs[64 * 32];

  const int tid = threadIdx.x;
  const int lane = tid & 63, wave = tid >> 6;
  const int wm = (wave >> 1) * 64, wn = (wave & 1) * 32;
  const int fm = lane & 15, fq = lane >> 4;
  const int kt = tid >> 4;          // 0..15 (k row within half-step)
  const int m8 = (tid & 15) * 8;    // 0..120
  const int br = tid >> 2, bkq = tid & 3;

  f32x4 acc[4][2];
  #pragma unroll
  for (int i = 0; i < 4; ++i) { acc[i][0] = (f32x4)(0.f); acc[i][1] = (f32x4)(0.f); }

  uint4 rA0, rA1, rB, nA0, nA1, nB;
  rA0 = *(const uint4*)(A + (size_t)kt * HW + m0 + m8);
  rA1 = *(const uint4*)(A + (size_t)(kt + 16) * HW + m0 + m8);
  rB  = *(const uint4*)(W + (size_t)(n0 + br) * HIDD + bkq * 8);

  for (int k0 = 0; k0 < HIDD; k0 += 32) {
    // stage A transposed-by-layout: As2[k][m] via 4x b32 each (2-way max conflict)
    #pragma unroll
    for (int i = 0; i < 4; ++i)
      *(unsigned*)&As2[kt * 130 + m8 + 2 * i] = ((const unsigned*)&rA0)[i];
    #pragma unroll
    for (int i = 0; i < 4; ++i)
      *(unsigned*)&As2[(kt + 16) * 130 + m8 + 2 * i] = ((const unsigned*)&rA1)[i];
    *(uint4*)(&Bs[br * 32 + bkq * 8]) = rB;
    __syncthreads();
    const int kn = (k0 + 32 < HIDD) ? k0 + 32 : k0;
    nA0 = *(const uint4*)(A + (size_t)(kn + kt) * HW + m0 + m8);
    nA1 = *(const uint4*)(A + (size_t)(kn + kt + 16) * HW + m0 + m8);
    nB  = *(const uint4*)(W + (size_t)(n0 + br) * HIDD + kn + bkq * 8);
    // A fragments via 8 scalar u16 reads (conflict-free: fq-groups hit disjoint
    // 8-bank windows since 520%32==8, 65%32==1)
    bf16x8 af[4];
    #pragma unroll
    for (int mt = 0; mt < 4; ++mt) {
      union { bf16x8 v; u16 h[8]; } t;
      const int m = wm + mt * 16 + fm;
      #pragma unroll
      for (int e = 0; e < 8; ++e)
        t.h[e] = As2[(fq * 8 + e) * 130 + m];
      af[mt] = t.v;
    }
    bf16x8 bf[2];
    #pragma unroll
    for (int nt = 0; nt < 2; ++nt)
      bf[nt] = *(const bf16x8*)(&Bs[(wn + nt * 16 + fm) * 32 + fq * 8]);
    #pragma unroll
    for (int mt = 0; mt < 4; ++mt)
      #pragma unroll
      for (int nt = 0; nt < 2; ++nt)
        acc[mt][nt] = __builtin_amdgcn_mfma_f32_16x16x32_bf16(af[mt], bf[nt], acc[mt][nt], 0, 0, 0);
    __syncthreads();
    rA0 = nA0; rA1 = nA1; rB = nB;
  }

  #pragma unroll
  for (int nt = 0; nt < 2; ++nt) {
    const int n = n0 + wn + nt * 16 + fm;
    const float bia = bias[n0 + wn + nt * 16 + fm];
    #pragma unroll
    for (int mt = 0; mt < 4; ++mt) {
      const int mb = m0 + wm + mt * 16 + fq * 4;
      const float4 ax = *(const float4*)(aux + (size_t)n * HW + mb);
      outTM[(size_t)(mb + 0) * CD + n] = acc[mt][nt][0] + bia + ax.x;
      outTM[(size_t)(mb + 1) * CD + n] = acc[mt][nt][1] + bia + ax.y;
      outTM[(size_t)(mb + 2) * CD + n] = acc[mt][nt][2] + bia + ax.z;
      outTM[(size_t)(mb + 3) * CD + n] = acc[mt][nt][3] + bia + ax.w;
    }
  }
}

// ---------- depthwise 5x5 conv + bias + exact GELU (+optional residual) ----------
template<bool ADD>
__global__ __launch_bounds__(256)
void dwconv_kernel(const u16* __restrict__ in, const float* __restrict__ w,
                   const float* __restrict__ bias, u16* __restrict__ out)
{
  const int plane = blockIdx.z;
  const int bx = blockIdx.x * 64, by = blockIdx.y * 4;
  __shared__ float tile[8][68];
  __shared__ float ws[26];
  const int tid = threadIdx.x;
  if (tid < 26) ws[tid] = (tid < 25) ? w[plane * 25 + tid] : bias[plane];
  const u16* ip = in + (size_t)plane * HW;
  for (int e = tid; e < 544; e += 256) {
    int r = e / 68, cc = e - r * 68;
    int gy = by + r - 2, gx = bx + cc - 2;
    tile[r][cc] = (gy >= 0 && gy < 192 && gx >= 0 && gx < 192) ? b2f(ip[gy * 192 + gx]) : 0.f;
  }
  __syncthreads();
  const int tx = tid & 63, ty = tid >> 6;
  float acc = 0.f;
  #pragma unroll
  for (int dy = 0; dy < 5; ++dy)
    #pragma unroll
    for (int dx = 0; dx < 5; ++dx)
      acc = fmaf(tile[ty + dy][tx + dx], ws[dy * 5 + dx], acc);
  float v = gelu_f(acc + ws[25]);
  if (ADD) v += tile[ty + 2][tx + 2];
  out[(size_t)plane * HW + (by + ty) * 192 + bx + tx] = f2b(v);
}

// ---------- fused window attention v8b ----------
// v5b structure + DPP wave reductions (no ds_bpermute) + rpi gather hoisted
// above the top barrier.
__global__ __launch_bounds__(512, 6)
void attn_kernel(const u16* __restrict__ qg, const u16* __restrict__ kg,
                 const u16* __restrict__ vg, const u16* __restrict__ vlg,
                 const float* __restrict__ pfa_v, const int* __restrict__ pfa_i,
                 const int* __restrict__ rpi, const float* __restrict__ rpb_t,
                 u16* __restrict__ attn_out)
{
  const int h = blockIdx.x;
  const int win = blockIdx.y;
  const int wy = (win / 12) * 16;
  const int wx = (win - (win / 12) * 12) * 16;
  const size_t hb = (size_t)h * HDIM * HW;

  __shared__ float Sb[32][262];   // scores / P rows, stride 1048B   33536 B (aliased as K staging [256][40] u16)
  __shared__ u16 vT[32][264];     // V^T [d][j] f16 bits             16896 B
  __shared__ u16 rpb_h[962];      // rpb bf16                         1924 B
                                  // total 52356 -> 52736 rounded -> 3 blk/CU

  const int tid = threadIdx.x;
  const int lane = tid & 63, wave = tid >> 6;
  const int fm = lane & 15, fq = lane >> 4;

  for (int r = tid; r < 961; r += 512) rpb_h[r] = f2b(rpb_t[r * 6 + h]);

  // stage K [256][40] u16 into Sb bytes, V^T (f16 bits) into vT
  u16* kst = (u16*)&Sb[0][0];
  #pragma unroll
  for (int r = 0; r < 8; ++r) {
    int idx = tid + r * 512;
    int d = idx >> 7, jp = idx & 127, j = jp * 2;
    int pg = (wy + (j >> 4)) * 192 + (wx + (j & 15));
    ushort2 kv = *(const ushort2*)(kg + hb + (size_t)d * HW + pg);
    kst[j * 40 + d] = kv.x; kst[(j + 1) * 40 + d] = kv.y;
    ushort2 vv = *(const ushort2*)(vg + hb + (size_t)d * HW + pg);
    *(unsigned*)&vT[d][j] = pkrtz_u(b2f(vv.x), b2f(vv.y));
  }
  __syncthreads();

  // hoist K fragments (pass-invariant) into 16 VGPRs
  bf16x8 kf[4];
  #pragma unroll
  for (int t = 0; t < 4; ++t) {
    const int j0 = ((wave >> 1) * 4 + t) * 16;
    kf[t] = *(const bf16x8*)&kst[(j0 + fm) * 40 + fq * 8];
  }
  // (pass-0 top barrier orders these reads before Sb score writes)

  const size_t wb = ((size_t)win * NH + h) * 256;
  const unsigned long long lmlt = (1ull << lane) - 1ull;
  const unsigned KMASK = 0xFFFFF800u;   // 21-bit selection key (bits 31..11)

  // preload pass-0 pfa
  int pj1[4], pj2[4]; float pv1[4], pv2[4];
  #pragma unroll
  for (int u = 0; u < 4; ++u) {
    const size_t base = (wb + (size_t)(u * 8 + wave)) * 128;
    pj1[u] = pfa_i[base + lane];  pj2[u] = pfa_i[base + 64 + lane];
    pv1[u] = pfa_v[base + lane];  pv2[u] = pfa_v[base + 64 + lane];
  }

  for (int pass = 0; pass < 8; ++pass) {
    // Q fragment straight from global (q already scaled by hd^-0.5)
    union { bf16x8 v; u16 hh[8]; } aqu;
    {
      const int pgq = (wy + pass * 2 + (wave & 1)) * 192 + wx + fm;
      #pragma unroll
      for (int e = 0; e < 8; ++e)
        aqu.hh[e] = qg[hb + (size_t)(fq * 8 + e) * HW + pgq];
    }
    // vl prefetch for the D epilogue (wave<4 only)
    float vlv[4];
    if (wave < 4) {
      const int mt = wave & 1, nt = wave >> 1;
      const int pgo = (wy + pass * 2 + nt) * 192 + wx + fm;
      const int d0 = mt * 16 + fq * 4;
      #pragma unroll
      for (int e = 0; e < 4; ++e)
        vlv[e] = b2f(vlg[hb + (size_t)(d0 + e) * HW + pgo]);
    }
    // rpi gather (pj resident since prev pass; window = barrier + B)
    int rbi1[4], rbi2[4];
    #pragma unroll
    for (int u = 0; u < 4; ++u) {
      const int i = pass * 32 + u * 8 + wave;
      rbi1[u] = rpi[i * 256 + pj1[u]];
      rbi2[u] = rpi[i * 256 + pj2[u]];
    }
    __syncthreads();   // prev-pass D reads of Sb done (and pass-0 kf reads)

    // B: scores via MFMA -> Sb
    #pragma unroll
    for (int t = 0; t < 4; ++t) {
      f32x4 c = __builtin_amdgcn_mfma_f32_16x16x32_bf16(aqu.v, kf[t], (f32x4)(0.f), 0, 0, 0);
      const int col = ((wave >> 1) * 4 + t) * 16 + fm;
      const int rowb = (wave & 1) * 16 + fq * 4;
      Sb[rowb + 0][col] = c[0]; Sb[rowb + 1][col] = c[1];
      Sb[rowb + 2][col] = c[2]; Sb[rowb + 3][col] = c[3];
    }
    __syncthreads();

    // C: batched 4-query phases (each wave owns rows u*8+wave)
    float s1[4], s2[4];
    #pragma unroll
    for (int u = 0; u < 4; ++u) {
      const int iq = u * 8 + wave;
      s1[u] = Sb[iq][pj1[u]] + b2f(rpb_h[rbi1[u]]);
      s2[u] = Sb[iq][pj2[u]] + b2f(rpb_h[rbi2[u]]);
    }
    // zero own rows (scores consumed); becomes the P scatter target
    {
      const float2 z2 = make_float2(0.f, 0.f);
      #pragma unroll
      for (int u = 0; u < 4; ++u) {
        const int iq = u * 8 + wave;
        *(float2*)&Sb[iq][lane * 4]     = z2;
        *(float2*)&Sb[iq][lane * 4 + 2] = z2;
      }
    }
    // wave reductions via DPP (VALU-only, no LDS)
    float mx[4];
    #pragma unroll
    for (int u = 0; u < 4; ++u) mx[u] = wave_max(fmaxf(s1[u], s2[u]));
    float e1[4], e2[4], sA[4], sB[4];
    #pragma unroll
    for (int u = 0; u < 4; ++u) {
      e1[u] = expf(s1[u] - mx[u]); e2[u] = expf(s2[u] - mx[u]);
    }
    #pragma unroll
    for (int u = 0; u < 4; ++u) {
      sA[u] = wave_sum(e1[u] + e2[u]);
      sB[u] = wave_sum(e1[u] * pv1[u] + e2[u] * pv2[u]);
    }
    unsigned ub1[4], ub2[4]; float a1[4], a2[4];
    #pragma unroll
    for (int u = 0; u < 4; ++u) {
      const float rs = 1.0f / sA[u];
      const float rden = 1.0f / (sB[u] * rs + 1e-10f);
      a1[u] = (e1[u] * rs * pv1[u] + 1e-10f) * rden;
      a2[u] = (e2[u] * rs * pv2[u] + 1e-10f) * rden;
      ub1[u] = __float_as_uint(a1[u]); ub2[u] = __float_as_uint(a2[u]);
    }
    // branchless batched radix select on 19-bit key (a < 2 => bit30 == 0)
    unsigned thr[4] = {0u, 0u, 0u, 0u};
    #pragma unroll 1
    for (int bit = 29; bit >= 11; --bit) {
      #pragma unroll
      for (int u = 0; u < 4; ++u) {
        const unsigned cand = thr[u] | (1u << bit);
        const int cnt = (int)__popcll(__ballot(ub1[u] >= cand)) +
                        (int)__popcll(__ballot(ub2[u] >= cand));
        thr[u] = (cnt >= 64) ? cand : thr[u];
      }
    }
    // tie-break on masked key (position order, matches jax top_k) and scatter-sum
    #pragma unroll
    for (int u = 0; u < 4; ++u) {
      const int iq = u * 8 + wave;
      const unsigned kb1 = ub1[u] & KMASK, kb2 = ub2[u] & KMASK;
      const bool gt1 = kb1 > thr[u], gt2 = kb2 > thr[u];
      const bool eq1 = kb1 == thr[u], eq2 = kb2 == thr[u];
      const unsigned long long meq1 = __ballot(eq1), meq2 = __ballot(eq2);
      const int need = 64 - (int)__popcll(__ballot(gt1)) - (int)__popcll(__ballot(gt2));
      const bool sel1 = gt1 || (eq1 && (int)__popcll(meq1 & lmlt) < need);
      const bool sel2 = gt2 || (eq2 && ((int)__popcll(meq1) + (int)__popcll(meq2 & lmlt)) < need);
      if (sel1) atomicAdd(&Sb[iq][pj1[u]], a1[u]);
      if (sel2) atomicAdd(&Sb[iq][pj2[u]], a2[u]);
    }
    // issue next pass's pfa loads (in flight across D + barrier + B)
    int npj1[4], npj2[4]; float npv1[4], npv2[4];
    {
      const int pnext = (pass + 1) & 7;
      #pragma unroll
      for (int u = 0; u < 4; ++u) {
        const size_t base = (wb + (size_t)(pnext * 32 + u * 8 + wave)) * 128;
        npj1[u] = pfa_i[base + lane];  npj2[u] = pfa_i[base + 64 + lane];
        npv1[u] = pfa_v[base + lane];  npv2[u] = pfa_v[base + 64 + lane];
      }
    }
    __syncthreads();

    // D: O = V^T (32d x 256j) . P^T (256j x 32i), single f16 MFMA per k0
    if (wave < 4) {
      const int mt = wave & 1, nt = wave >> 1;
      f32x4 acc = (f32x4)(0.f);
      #pragma unroll
      for (int k0 = 0; k0 < 8; ++k0) {
        const f16x8 av = *(const f16x8*)&vT[mt * 16 + fm][k0 * 32 + fq * 8];
        const float* pr = &Sb[nt * 16 + fm][k0 * 32 + fq * 8];
        const float2 p01 = *(const float2*)(pr + 0);
        const float2 p23 = *(const float2*)(pr + 2);
        const float2 p45 = *(const float2*)(pr + 4);
        const float2 p67 = *(const float2*)(pr + 6);
        union { f16x8 v; unsigned q[4]; } bp;
        bp.q[0] = pkrtz_u(p01.x, p01.y);
        bp.q[1] = pkrtz_u(p23.x, p23.y);
        bp.q[2] = pkrtz_u(p45.x, p45.y);
        bp.q[3] = pkrtz_u(p67.x, p67.y);
        acc = __builtin_amdgcn_mfma_f32_16x16x32_f16(av, bp.v, acc, 0, 0, 0);
      }
      // epilogue: D row = d-within-tile, col = i-within-tile
      const int pgo = (wy + pass * 2 + nt) * 192 + wx + fm;
      const int d0 = mt * 16 + fq * 4;
      const float r0 = acc[0] + vlv[0];
      const float r1 = acc[1] + vlv[1];
      const float r2 = acc[2] + vlv[2];
      const float r3 = acc[3] + vlv[3];
      const unsigned o01 = (unsigned)f2b(r0) | ((unsigned)f2b(r1) << 16);
      const unsigned o23 = (unsigned)f2b(r2) | ((unsigned)f2b(r3) << 16);
      *(uint2*)(attn_out + (size_t)pgo * CD + h * HDIM + d0) = make_uint2(o01, o23);
    }
    // rotate pfa pipeline
    #pragma unroll
    for (int u = 0; u < 4; ++u) {
      pj1[u] = npj1[u]; pj2[u] = npj2[u];
      pv1[u] = npv1[u]; pv2[u] = npv2[u];
    }
  }
}

// ---------- launch ----------
extern "C" void kernel_launch(void* const* d_in, const int* in_sizes, int n_in,
                              void* d_out, int out_size, void* d_ws, size_t ws_size,
                              hipStream_t stream)
{
  (void)in_sizes; (void)n_in; (void)out_size; (void)ws_size;
  const float* features = (const float*)d_in[0];
  const float* pfa_v    = (const float*)d_in[1];
  const int*   pfa_i    = (const int*)d_in[2];
  const int*   rpi      = (const int*)d_in[3];
  const float* ln1_g    = (const float*)d_in[4];
  const float* ln1_b    = (const float*)d_in[5];
  const float* Wq_w     = (const float*)d_in[6];
  const float* Wq_b     = (const float*)d_in[7];
  const float* Wk_w     = (const float*)d_in[8];
  const float* Wk_b     = (const float*)d_in[9];
  const float* Wv_w     = (const float*)d_in[10];
  const float* Wv_b     = (const float*)d_in[11];
  const float* lepe_w   = (const float*)d_in[12];
  const float* lepe_b   = (const float*)d_in[13];
  const float* rpb_t    = (const float*)d_in[14];
  const float* proj_w   = (const float*)d_in[15];
  const float* proj_b   = (const float*)d_in[16];
  const float* ln2_g    = (const float*)d_in[17];
  const float* ln2_b    = (const float*)d_in[18];
  const float* fc1_w    = (const float*)d_in[19];
  const float* fc1_b    = (const float*)d_in[20];
  const float* dw_w     = (const float*)d_in[21];
  const float* dw_b     = (const float*)d_in[22];
  const float* fc2_w    = (const float*)d_in[23];
  const float* fc2_b    = (const float*)d_in[24];

  char* ws = (char*)d_ws;
  const size_t S  = (size_t)HW * CD;
  const size_t SB = S * 4;
  u16*   xnt    = (u16*)(ws);                         // [0, 0.5SB) bf16 TM
  u16*   qkvb   = (u16*)(ws + SB / 2);                // [0.5SB, 2SB) bf16 CM (q scaled, k, v)
  u16*   q_ = qkvb; u16* k_ = qkvb + S; u16* v_ = qkvb + 2 * S;
  u16*   vl     = (u16*)(ws + 2 * SB);                // [2SB, 2.5SB)
  u16*   attn_o = (u16*)(ws + 2 * SB + SB / 2);       // [2.5SB, 3SB) bf16 TM
  float* x2     = (float*)(ws + 3 * SB);              // [3SB, 4SB) fp32 CM, live to end
  u16*   xn2t   = (u16*)(ws + 4 * SB);                // [4SB, 4.5SB)
  u16*   y_     = (u16*)(ws + 4 * SB + SB / 2);       // [4.5SB, 6.5SB) bf16 CM 768xHW
  u16*   y2_    = (u16*)(ws + 6 * SB + SB / 2);       // [6.5SB, 8.5SB)
  u16*   wqt  = (u16*)(ws + 8 * SB + SB / 2);
  u16*   wkt  = wqt + 36864;
  u16*   wvt  = wkt + 36864;
  u16*   wpt  = wvt + 36864;
  u16*   wf1t = wpt + 36864;      // [768][192]
  u16*   wf2t = wf1t + 147456;    // [192][768]
  float* out = (float*)d_out;

  // 0) weight prep
  wtrans4_kernel<<<dim3(6, 6, 4), 256, 0, stream>>>(Wq_w, Wk_w, Wv_w, proj_w, wqt);
  wtrans_kernel<<<dim3(6, 24), 256, 0, stream>>>(fc1_w, wf1t, 192, 768);
  wtrans_kernel<<<dim3(24, 6), 256, 0, stream>>>(fc2_w, wf2t, 768, 192);
  // 1) LN1 fused transpose -> bf16 TM
  lnt_kernel<<<dim3(HW / 64), 256, 0, stream>>>(features, ln1_g, ln1_b, xnt);
  // 2) QKV MFMA -> bf16 CM (q scaled)
  mgemm_kernel<0><<<dim3(9, HW / 128), 256, 0, stream>>>(xnt, wqt, wkt, wvt, Wq_b, Wk_b, Wv_b,
                                                         nullptr, qkvb, 192, 192);
  // 3) LePE dwconv on v (bf16)
  dwconv_kernel<false><<<dim3(3, 48, 192), 256, 0, stream>>>(v_, lepe_w, lepe_b, vl);
  // 4) window attention -> bf16 TM
  attn_kernel<<<dim3(6, 144), 512, 0, stream>>>(q_, k_, v_, vl, pfa_v, pfa_i, rpi, rpb_t, attn_o);
  // 5) proj + shortcut -> fp32 CM x2
  mgemm_kernel<1><<<dim3(3, HW / 128), 256, 0, stream>>>(attn_o, wpt, wpt, wpt, proj_b, proj_b, proj_b,
                                                         features, x2, 192, 1 << 30);
  // 6) LN2 fused transpose -> bf16 TM
  lnt_kernel<<<dim3(HW / 64), 256, 0, stream>>>(x2, ln2_g, ln2_b, xn2t);
  // 7) fc1 + GELU -> bf16 CM y
  mgemm_kernel<2><<<dim3(12, HW / 128), 256, 0, stream>>>(xn2t, wf1t, wf1t, wf1t, fc1_b, fc1_b, fc1_b,
                                                          nullptr, y_, 192, 1 << 30);
  // 8) y2 = y + gelu(dwconv(y)+b) -> bf16 CM
  dwconv_kernel<true><<<dim3(3, 48, 768), 256, 0, stream>>>(y_, dw_w, dw_b, y2_);
  // 9) fc2 reads y2 CM directly (transpose-staged) + x2 residual -> fp32 TM out
  fc2_kernel<<<dim3(3, HW / 128), 256, 0, stream>>>(y2_, wf2t, fc2_b, x2, out);
}